// Round 7
// baseline (262.371 us; speedup 1.0000x reference)
//
#include <hip/hip_runtime.h>
#include <hip/hip_bf16.h>
#include <hip/hip_fp16.h>

#define D_MODEL 1024
#define N_SEQ   2048
#define N_B     2
#define M_ROWS  (N_B * N_SEQ)   // 4096

typedef __attribute__((ext_vector_type(8))) short bf16x8;
typedef __attribute__((ext_vector_type(4))) float f32x4;

typedef const __attribute__((address_space(1))) unsigned int gu32_t;
typedef __attribute__((address_space(3))) unsigned int lu32_t;

__device__ __forceinline__ void gload16(const void* g, void* l) {
  // async global->LDS, 16B per lane; LDS dest = wave-uniform base + lane*16
  __builtin_amdgcn_global_load_lds((gu32_t*)g, (lu32_t*)l, 16, 0, 0);
}

__device__ inline unsigned short f2bf(float f) {
  union { float f; unsigned int u; } v; v.f = f;
  unsigned int r = (v.u + 0x7FFFu + ((v.u >> 16) & 1u)) >> 16;
  return (unsigned short)r;
}

// packed f32x2 -> bf16x2 (RNE); no builtin on gfx950, per learn_hip m240
__device__ __forceinline__ unsigned int cvt_pk_bf16(float a, float b) {
  unsigned int r;
  asm("v_cvt_pk_bf16_f32 %0, %1, %2" : "=v"(r) : "v"(a), "v"(b));
  return r;
}

__device__ __forceinline__ float exp2fast(float x) {
#if __has_builtin(__builtin_amdgcn_exp2f)
  return __builtin_amdgcn_exp2f(x);
#else
  return __expf(x * 0.69314718056f);
#endif
}

// counted vmcnt wait (T4): never drain to 0 in the main loop
#define WAITV(N) asm volatile("s_waitcnt vmcnt(" #N ")" ::: "memory")

// Bank-conflict swizzle for 64-col (128B-row) LDS tiles:
// logical 16B-chunk k of row r lives at physical chunk k ^ (r & 7).
__device__ __forceinline__ int lds_off(int row, int col /*ushort idx*/) {
  return row * 64 + (((col >> 3) ^ (row & 7)) << 3) + (col & 7);
}

// Stage a ROWS x 64-ushort tile global->LDS with the swizzle applied on the
// global-source side (LDS destination must stay linear for global_load_lds).
template<int ROWS, int NTHR = 256>
__device__ __forceinline__ void stage_tile(const unsigned short* gbase, size_t gstride,
                                           unsigned short* lds, int tid) {
  const int wave = tid >> 6;
#pragma unroll
  for (int rnd = 0; rnd < ROWS * 8 / NTHR; ++rnd) {
    int c = rnd * NTHR + tid;
    int row = c >> 3, pc = c & 7;
    int gcol = ((pc ^ (row & 7)) << 3);
    gload16(gbase + (size_t)row * gstride + gcol,
            lds + (size_t)(rnd * NTHR + wave * 64) * 8);
  }
}

constexpr size_t XEL = (size_t)M_ROWS * D_MODEL;     // 4194304
constexpr size_t WEL = (size_t)D_MODEL * D_MODEL;    // 1048576
constexpr size_t BEL = (size_t)N_B * N_SEQ * N_SEQ;  // 8388608 (attn bias)
constexpr size_t TOTEL = XEL + 4 * WEL + BEL;        // 16777216

// ---------------------------------------------------------------------------
// fp32 -> bf16 convert for [x (4M) | Wq | Wk | Wv | Wo (1M each)] -> dst,
// plus fp32 -> f16 for attn bias (8M) -> dstB (halves attn's dominant
// L2/L3 bias stream; f16 e5m10 keeps |err| ~2^-11 rel, well under bf16 floor).
// ---------------------------------------------------------------------------
__launch_bounds__(256)
__global__ void cvt_kernel(const float* __restrict__ x, const float* __restrict__ bias,
                           const float* __restrict__ wq, const float* __restrict__ wk,
                           const float* __restrict__ wv, const float* __restrict__ wo,
                           unsigned short* __restrict__ dst,
                           unsigned short* __restrict__ dstB) {
  size_t i = ((size_t)blockIdx.x * 256 + threadIdx.x) * 8;
  if (i >= TOTEL) return;
  if (i >= XEL + 4 * WEL) {
    size_t off = i - (XEL + 4 * WEL);
    float4 f0 = *(const float4*)(bias + off);
    float4 f1 = *(const float4*)(bias + off + 4);
    __half t[8] = { __float2half(f0.x), __float2half(f0.y), __float2half(f0.z),
                    __float2half(f0.w), __float2half(f1.x), __float2half(f1.y),
                    __float2half(f1.z), __float2half(f1.w) };
    *(uint4*)(dstB + off) = *(const uint4*)t;
    return;
  }
  const float* s; size_t off = i;
  if (off < XEL)                { s = x; }
  else if (off < XEL + WEL)     { s = wq; off -= XEL; }
  else if (off < XEL + 2*WEL)   { s = wk; off -= XEL + WEL; }
  else if (off < XEL + 3*WEL)   { s = wv; off -= XEL + 2*WEL; }
  else                          { s = wo; off -= XEL + 3*WEL; }
  float4 f0 = *(const float4*)(s + off);
  float4 f1 = *(const float4*)(s + off + 4);
  unsigned short t[8] = { f2bf(f0.x), f2bf(f0.y), f2bf(f0.z), f2bf(f0.w),
                          f2bf(f1.x), f2bf(f1.y), f2bf(f1.z), f2bf(f1.w) };
  *(uint4*)(dst + i) = *(const uint4*)t;
}

// ---------------------------------------------------------------------------
// m97-style 128x128 bf16 mainloop, swizzled LDS: C = A * Bw^T
// ---------------------------------------------------------------------------
__device__ __forceinline__ void mainloop128(const unsigned short* __restrict__ A,
                                            const unsigned short* __restrict__ Bw,
                                            int m0, int e0,
                                            unsigned short* As, unsigned short* Bs,
                                            f32x4 (&acc)[4][4]) {
  const int tid  = threadIdx.x;
  const int wave = tid >> 6, lane = tid & 63;
  const int l16 = lane & 15, quad = lane >> 4;
  const int wr = wave >> 1, wc = wave & 1;

  for (int kt = 0; kt < D_MODEL / 64; ++kt) {
    const int k0 = kt * 64;
    stage_tile<128>(A + (size_t)m0 * D_MODEL + k0, D_MODEL, As, tid);
    stage_tile<128>(Bw + (size_t)e0 * D_MODEL + k0, D_MODEL, Bs, tid);
    __syncthreads();
#pragma unroll
    for (int ks = 0; ks < 2; ++ks) {
      bf16x8 af[4], bfr[4];
#pragma unroll
      for (int mi = 0; mi < 4; ++mi)
        af[mi] = *(const bf16x8*)(As + lds_off(wr * 64 + mi * 16 + l16, ks * 32 + quad * 8));
#pragma unroll
      for (int ci = 0; ci < 4; ++ci)
        bfr[ci] = *(const bf16x8*)(Bs + lds_off(wc * 64 + ci * 16 + l16, ks * 32 + quad * 8));
#pragma unroll
      for (int mi = 0; mi < 4; ++mi)
#pragma unroll
        for (int ci = 0; ci < 4; ++ci)
          acc[mi][ci] = __builtin_amdgcn_mfma_f32_16x16x32_bf16(af[mi], bfr[ci], acc[mi][ci], 0, 0, 0);
    }
    __syncthreads();
  }
}

// ---------------------------------------------------------------------------
// Fused Q/K/V projection. grid (32, 24): by -> {mat = by>>3, e0 = (by&7)*128}.
// mat 0 (q): LN epilogue with 0.125*log2e softmax/exp2 scale folded in.
// mat 1 (k): LN epilogue.
// mat 2 (v): V stored TRANSPOSED per (b,h), keys sigma-permuted within each
//            32-block so attn's in-register P^T fragment lines up with V.
// ---------------------------------------------------------------------------
__launch_bounds__(256)
__global__ void qkv_gemm(const unsigned short* __restrict__ xb,
                         const unsigned short* __restrict__ wb,   // wq|wk|wv bf16
                         const float* __restrict__ bq, const float* __restrict__ bk,
                         const float* __restrict__ bv,
                         const float* __restrict__ qg, const float* __restrict__ qbeta,
                         const float* __restrict__ kg, const float* __restrict__ kbeta,
                         unsigned short* __restrict__ qkout,      // qn | kn
                         unsigned short* __restrict__ vt) {
  __shared__ unsigned short As[128 * 64];
  __shared__ unsigned short Bs[128 * 64];
  const int m0  = blockIdx.x * 128;
  const int by  = blockIdx.y;
  const int mat = by >> 3;
  const int e0  = (by & 7) * 128;
  const unsigned short* Bw = wb + (size_t)mat * WEL;

  f32x4 acc[4][4];
#pragma unroll
  for (int mi = 0; mi < 4; ++mi)
#pragma unroll
    for (int ci = 0; ci < 4; ++ci) acc[mi][ci] = f32x4{0.f, 0.f, 0.f, 0.f};

  mainloop128(xb, Bw, m0, e0, As, Bs, acc);

  const int lane = threadIdx.x & 63, wave = threadIdx.x >> 6;
  const int l16 = lane & 15, quad = lane >> 4;
  const int wr = wave >> 1, wc = wave & 1;
  const int colbase = e0 + wc * 64;          // multiple of 64 -> one head per wave

  const float* bias = (mat == 0) ? bq : ((mat == 1) ? bk : bv);
  float bcol[4];
#pragma unroll
  for (int ci = 0; ci < 4; ++ci) bcol[ci] = bias[colbase + ci * 16 + l16];
#pragma unroll
  for (int mi = 0; mi < 4; ++mi)
#pragma unroll
    for (int ci = 0; ci < 4; ++ci)
#pragma unroll
      for (int r = 0; r < 4; ++r) acc[mi][ci][r] += bcol[ci];

  if (mat < 2) {
    const float* gamma = (mat == 0) ? qg : kg;
    const float* beta  = (mat == 0) ? qbeta : kbeta;
    // fold softmax scale AND log2(e) (attn uses exp2) into q
    const float sc = (mat == 0) ? 0.18033688011112042f : 1.0f;  // 0.125*log2e
    float g4[4], bt4[4];
#pragma unroll
    for (int ci = 0; ci < 4; ++ci) {
      g4[ci] = gamma[ci * 16 + l16] * sc;
      bt4[ci] = beta[ci * 16 + l16] * sc;
    }
#pragma unroll
    for (int mi = 0; mi < 4; ++mi)
#pragma unroll
      for (int r = 0; r < 4; ++r) {
        float s = acc[mi][0][r] + acc[mi][1][r] + acc[mi][2][r] + acc[mi][3][r];
        s += __shfl_xor(s, 1); s += __shfl_xor(s, 2);
        s += __shfl_xor(s, 4); s += __shfl_xor(s, 8);
        float mean = s * (1.f / 64.f);
        float d0 = acc[mi][0][r] - mean, d1 = acc[mi][1][r] - mean;
        float d2 = acc[mi][2][r] - mean, d3 = acc[mi][3][r] - mean;
        float q = d0 * d0 + d1 * d1 + d2 * d2 + d3 * d3;
        q += __shfl_xor(q, 1); q += __shfl_xor(q, 2);
        q += __shfl_xor(q, 4); q += __shfl_xor(q, 8);
        float rs = rsqrtf(q * (1.f / 64.f) + 1e-6f);
        acc[mi][0][r] = d0 * rs * g4[0] + bt4[0];
        acc[mi][1][r] = d1 * rs * g4[1] + bt4[1];
        acc[mi][2][r] = d2 * rs * g4[2] + bt4[2];
        acc[mi][3][r] = d3 * rs * g4[3] + bt4[3];
      }
    unsigned short* out = qkout + (size_t)mat * XEL;
#pragma unroll
    for (int mi = 0; mi < 4; ++mi)
#pragma unroll
      for (int ci = 0; ci < 4; ++ci) {
        int col = colbase + ci * 16 + l16;
#pragma unroll
        for (int r = 0; r < 4; ++r) {
          int row = m0 + wr * 64 + mi * 16 + quad * 4 + r;
          out[(size_t)row * D_MODEL + col] = f2bf(acc[mi][ci][r]);
        }
      }
  } else {
    // V transpose via wave-private LDS scratch (col-swizzled), then each lane
    // stores one full d-row (128B) as 8x dwordx4 -> coalesced.
    // Token index within 64 is sigma-permuted: logical t = 16*half+4*q+r
    // stored at phys = 8*q + 4*half + r (within its 32-block), matching the
    // attention kernel's in-register P^T bf16x8 fragment order.
    unsigned short* scr = ((wave < 2) ? As : Bs) + (size_t)(wave & 1) * 4096;
#pragma unroll
    for (int ci = 0; ci < 4; ++ci) {
      int dl = ci * 16 + l16;
      int sw = (dl & 3) * 16;
#pragma unroll
      for (int mi = 0; mi < 4; ++mi)
#pragma unroll
        for (int r = 0; r < 4; ++r) {
          // logical token t = mi*16 + quad*4 + r  (half = mi&1, block = mi>>1)
          int np = ((mi >> 1) << 5) + (quad << 3) + ((mi & 1) << 2) + r;
          scr[dl * 64 + (np ^ sw)] = f2bf(acc[mi][ci][r]);
        }
    }
    __builtin_amdgcn_wave_barrier();
    int row0 = m0 + wr * 64;                 // token base of this wave's tile
    int b = row0 >> 11, nb = row0 & 2047;
    int h = colbase >> 6;
    int dl = lane;                           // this lane's d within the head
    unsigned short* gdst = vt + ((size_t)((b * 16 + h) * 64 + dl) * N_SEQ + nb);
    const unsigned short* srow = scr + dl * 64;
    int sw = (dl & 3) * 16;
#pragma unroll
    for (int j = 0; j < 8; ++j) {
      uint4 vv = *(const uint4*)(srow + ((j * 8) ^ sw));
      *(uint4*)(gdst + j * 8) = vv;
    }
  }
}

// ---------------------------------------------------------------------------
// Output projection: fp32 out = ao * Wo^T + bo. grid (32, 8).
// ---------------------------------------------------------------------------
__launch_bounds__(256)
__global__ void out_gemm(const unsigned short* __restrict__ ao,
                         const unsigned short* __restrict__ wob,
                         const float* __restrict__ bo,
                         float* __restrict__ out) {
  __shared__ unsigned short As[128 * 64];
  __shared__ unsigned short Bs[128 * 64];
  const int m0 = blockIdx.x * 128;
  const int e0 = blockIdx.y * 128;

  f32x4 acc[4][4];
#pragma unroll
  for (int mi = 0; mi < 4; ++mi)
#pragma unroll
    for (int ci = 0; ci < 4; ++ci) acc[mi][ci] = f32x4{0.f, 0.f, 0.f, 0.f};

  mainloop128(ao, wob, m0, e0, As, Bs, acc);

  const int lane = threadIdx.x & 63, wave = threadIdx.x >> 6;
  const int l16 = lane & 15, quad = lane >> 4;
  const int wr = wave >> 1, wc = wave & 1;
  float bcol[4];
#pragma unroll
  for (int ci = 0; ci < 4; ++ci) bcol[ci] = bo[e0 + wc * 64 + ci * 16 + l16];
#pragma unroll
  for (int mi = 0; mi < 4; ++mi)
#pragma unroll
    for (int ci = 0; ci < 4; ++ci) {
      int col = e0 + wc * 64 + ci * 16 + l16;
#pragma unroll
      for (int r = 0; r < 4; ++r) {
        int row = m0 + wr * 64 + mi * 16 + quad * 4 + r;
        out[(size_t)row * D_MODEL + col] = acc[mi][ci][r] + bcol[ci];
      }
    }
}

// ---------------------------------------------------------------------------
// Flash attention, swapped-operand QK^T, 8 waves / 512 threads per block.
// Wave pair (2p, 2p+1): wave 2p keys [0,32), wave 2p+1 keys [32,64) of the
// shared q-rows [p*32, p*32+32).
// R7: bias read from the f16 side-cache (built in cvt_kernel) -> the dominant
// L2/L3 stream (512 MB of fp32 across the grid) halves to 256 MB. R3..R6
// showed 85-92 us invariant across {occupancy, pipelining, setprio}: the wall
// is the bias stream, not scheduling. Bias loads are 4x8B (uint2) per wave
// per iter, unpacked with v_cvt_f32_f16 (+4 VALU per 16 keys); issue moved
// to post-exp (pre-PV) for ~150cy more latency cover. Ledger unchanged:
// per-iter VMEM = stage(2, top) + bias(4, post-exp) -> WAITV(6).
// Depth-3 K/V pipeline at 48KB LDS, Q overlaying K-bufs in the prologue.
// ---------------------------------------------------------------------------
__launch_bounds__(512)
__global__ void attn_kernel(const unsigned short* __restrict__ Q,
                            const unsigned short* __restrict__ Kn,
                            const unsigned short* __restrict__ Vt,
                            const unsigned short* __restrict__ bias16,  // f16
                            unsigned short* __restrict__ Out) {
  __shared__ unsigned short smem[24576];     // 48KB

  const int tid  = threadIdx.x;
  const int wave = tid >> 6, lane = tid & 63;
  const int quad = lane >> 4, l16 = lane & 15;
  const int pairId = wave >> 1;              // 4 pairs x 32 q-rows
  const int kh = wave & 1;                   // key half of the 64-key tile
  const int bidx = blockIdx.x;
  const int qt = bidx & 15;                  // 16 q-tiles of 128
  const int h  = (bidx >> 4) & 15;
  const int b  = bidx >> 8;
  const int q0 = qt * 128;
  const size_t base  = (size_t)b * N_SEQ * D_MODEL + (size_t)h * 64;
  const unsigned short* vtb = Vt + (size_t)(b * 16 + h) * 64 * N_SEQ;

  // bias row pointers for this lane's q-rows (S^T layout: q = l16), f16 elems
  const unsigned short* brow[2];
#pragma unroll
  for (int mi = 0; mi < 2; ++mi)
    brow[mi] = bias16 + ((size_t)b * N_SEQ + q0 + pairId * 32 + mi * 16 + l16) * N_SEQ;
  const int bcol0 = kh * 32 + quad * 4;      // this wave's key columns

  // ---- prologue phase 1: Q through LDS (overlays K-bufs 0/1), to regs ----
  stage_tile<128, 512>(Q + base + (size_t)q0 * D_MODEL, D_MODEL, smem, tid);
  __syncthreads();                           // Q DMA landed (vmcnt0) + barrier

  bf16x8 aq[2][2];                           // [mi][ks] — shared by the pair
#pragma unroll
  for (int mi = 0; mi < 2; ++mi)
#pragma unroll
    for (int ks = 0; ks < 2; ++ks)
      aq[mi][ks] = *(const bf16x8*)(smem + lds_off(pairId * 32 + mi * 16 + l16, ks * 32 + quad * 8));
  __syncthreads();                           // all waves read Q; safe to reuse

  // ---- prologue phase 2: bias tile 0 + stage K/V tiles 0,1 ----
  uint2 bcur[2][2];                          // 4 x 8B = 16 f16 bias values
#pragma unroll
  for (int mi = 0; mi < 2; ++mi)
#pragma unroll
    for (int cl = 0; cl < 2; ++cl)
      bcur[mi][cl] = *(const uint2*)(brow[mi] + bcol0 + cl * 16);

  stage_tile<64, 512>(Kn + base, D_MODEL, smem, tid);
  stage_tile<64, 512>(vtb, N_SEQ, smem + 12288, tid);
  stage_tile<64, 512>(Kn + base + (size_t)64 * D_MODEL, D_MODEL, smem + 4096, tid);
  stage_tile<64, 512>(vtb + 64, N_SEQ, smem + 12288 + 4096, tid);

  WAITV(2);                                  // bias+tile0 done; tile1 in flight
  __builtin_amdgcn_s_barrier();
  __builtin_amdgcn_sched_barrier(0);

  f32x4 o[2][4];                             // O^T partial: d = cd*16+quad*4+r, q = l16
#pragma unroll
  for (int mi = 0; mi < 2; ++mi)
#pragma unroll
    for (int cd = 0; cd < 4; ++cd) o[mi][cd] = f32x4{0.f, 0.f, 0.f, 0.f};
  float lsum[2] = {0.f, 0.f};
  constexpr float LOG2E = 1.44269504088896340736f;

  constexpr int NT = N_SEQ / 64;
  for (int kt = 0; kt < NT; ++kt) {
    const int cur = kt % 3;
    unsigned short* Kcur = smem + cur * 4096;
    unsigned short* Vcur = smem + 12288 + cur * 4096;

    // stage tile kt+2 into buf (kt+2)%3 (read last at iteration kt-1;
    // the barrier at end of kt-1 made it safe to overwrite)
    if (kt + 2 < NT) {
      const int nb = (kt + 2) % 3;
      stage_tile<64, 512>(Kn + base + (size_t)(kt + 2) * 64 * D_MODEL, D_MODEL,
                          smem + nb * 4096, tid);
      stage_tile<64, 512>(vtb + (kt + 2) * 64, N_SEQ,
                          smem + 12288 + nb * 4096, tid);
    }

    // S^T = K Q^T for this wave's 32 keys (q pre-scaled by 0.125*log2e)
    f32x4 sfT[2][2];                         // [mi][cl]: key = kh*32+cl*16+quad*4+r, q = l16
#pragma unroll
    for (int cl = 0; cl < 2; ++cl) {
      const int c = kh * 2 + cl;
      bf16x8 k0 = *(const bf16x8*)(Kcur + lds_off(c * 16 + l16, quad * 8));
      bf16x8 k1 = *(const bf16x8*)(Kcur + lds_off(c * 16 + l16, 32 + quad * 8));
      __builtin_amdgcn_s_setprio(1);
#pragma unroll
      for (int mi = 0; mi < 2; ++mi) {
        f32x4 z = f32x4{0.f, 0.f, 0.f, 0.f};
        z = __builtin_amdgcn_mfma_f32_16x16x32_bf16(k0, aq[mi][0], z, 0, 0, 0);
        sfT[mi][cl] = __builtin_amdgcn_mfma_f32_16x16x32_bf16(k1, aq[mi][1], z, 0, 0, 0);
      }
      __builtin_amdgcn_s_setprio(0);
    }

    // p = 2^(sT + bias*log2e); f16 bias unpacked via v_cvt_f32_f16.
    // paf k-slot order matches the sigma-permuted Vt layout.
    union PafU { unsigned int w[4]; bf16x8 v; };
    PafU paf[2];
#pragma unroll
    for (int mi = 0; mi < 2; ++mi)
#pragma unroll
      for (int cl = 0; cl < 2; ++cl) {
        uint2 bw = bcur[mi][cl];
        float2 fa = __half22float2(*(const __half2*)&bw.x);
        float2 fb = __half22float2(*(const __half2*)&bw.y);
        float p0 = exp2fast(fmaf(fa.x, LOG2E, sfT[mi][cl][0]));
        float p1 = exp2fast(fmaf(fa.y, LOG2E, sfT[mi][cl][1]));
        float p2 = exp2fast(fmaf(fb.x, LOG2E, sfT[mi][cl][2]));
        float p3 = exp2fast(fmaf(fb.y, LOG2E, sfT[mi][cl][3]));
        lsum[mi] += (p0 + p1) + (p2 + p3);
        paf[mi].w[cl * 2]     = cvt_pk_bf16(p0, p1);
        paf[mi].w[cl * 2 + 1] = cvt_pk_bf16(p2, p3);
      }

    // bias kt+1 -> bcur NOW (dead after exp above; WAR keeps loads ordered
    // after the exp reads). Latency cover: PV + WAITV/barrier + QK of kt+1.
    if (kt + 1 < NT) {
#pragma unroll
      for (int mi = 0; mi < 2; ++mi)
#pragma unroll
        for (int cl = 0; cl < 2; ++cl)
          bcur[mi][cl] = *(const uint2*)(brow[mi] + (kt + 1) * 64 + bcol0 + cl * 16);
    }

    // O^T += V^T P^T over this wave's 32 keys (V frags reused across both mi)
    {
      bf16x8 bv[4];
#pragma unroll
      for (int cd = 0; cd < 4; ++cd)
        bv[cd] = *(const bf16x8*)(Vcur + lds_off(cd * 16 + l16, kh * 32 + quad * 8));
      __builtin_amdgcn_s_setprio(1);
#pragma unroll
      for (int mi = 0; mi < 2; ++mi)
#pragma unroll
        for (int cd = 0; cd < 4; ++cd)
          o[mi][cd] = __builtin_amdgcn_mfma_f32_16x16x32_bf16(bv[cd], paf[mi].v, o[mi][cd], 0, 0, 0);
      __builtin_amdgcn_s_setprio(0);
    }

    // counted wait: guarantee tile kt+1 (staged at kt-1) landed, leave this
    // iteration's stage(2)+bias(4) in flight; raw barrier (no vmcnt(0) drain)
    if (kt + 1 < NT) {
      if (kt < NT - 2) { WAITV(6); } else { WAITV(4); }
      __builtin_amdgcn_s_barrier();
      __builtin_amdgcn_sched_barrier(0);
    }
  }

  // drain any stragglers before reusing K-buffer LDS as reduction scratch
  WAITV(0);
  __syncthreads();

  // ---- pair reduction: odd wave dumps partial O + lsum to (dead) LDS ----
  float* red = (float*)smem;                 // need 8704 floats = 34816B < 48KB
  float* slot = red + (size_t)(pairId * 64 + lane) * 34;
  if (kh) {
#pragma unroll
    for (int mi = 0; mi < 2; ++mi)
#pragma unroll
      for (int cd = 0; cd < 4; ++cd)
#pragma unroll
        for (int r = 0; r < 4; ++r)
          slot[mi * 16 + cd * 4 + r] = o[mi][cd][r];
    slot[32] = lsum[0];
    slot[33] = lsum[1];
  }
  __syncthreads();
  if (!kh) {
#pragma unroll
    for (int mi = 0; mi < 2; ++mi)
#pragma unroll
      for (int cd = 0; cd < 4; ++cd)
#pragma unroll
        for (int r = 0; r < 4; ++r)
          o[mi][cd][r] += slot[mi * 16 + cd * 4 + r];
    lsum[0] += slot[32];
    lsum[1] += slot[33];

    // normalize: lsum and O^T columns are both indexed by q = l16 -> lane-local
#pragma unroll
    for (int mi = 0; mi < 2; ++mi) {
      float l = lsum[mi];
      l += __shfl_xor(l, 16);
      l += __shfl_xor(l, 32);
      float inv = 1.0f / l;
      size_t row = (size_t)b * N_SEQ + q0 + pairId * 32 + mi * 16 + l16;
#pragma unroll
      for (int cd = 0; cd < 4; ++cd) {
        uint2 vv;
        vv.x = cvt_pk_bf16(o[mi][cd][0] * inv, o[mi][cd][1] * inv);
        vv.y = cvt_pk_bf16(o[mi][cd][2] * inv, o[mi][cd][3] * inv);
        *(uint2*)(Out + row * D_MODEL + h * 64 + cd * 16 + quad * 4) = vv;
      }
    }
  }
}

extern "C" void kernel_launch(void* const* d_in, const int* in_sizes, int n_in,
                              void* d_out, int out_size, void* d_ws, size_t ws_size,
                              hipStream_t stream) {
  const float* x    = (const float*)d_in[0];
  const float* bias = (const float*)d_in[1];
  const float* Wq = (const float*)d_in[2];  const float* bq = (const float*)d_in[3];
  const float* Wk = (const float*)d_in[4];  const float* bk = (const float*)d_in[5];
  const float* Wv = (const float*)d_in[6];  const float* bv = (const float*)d_in[7];
  const float* Wo = (const float*)d_in[8];  const float* bo = (const float*)d_in[9];
  const float* qg = (const float*)d_in[10]; const float* qb = (const float*)d_in[11];
  const float* kg = (const float*)d_in[12]; const float* kb = (const float*)d_in[13];
  float* out = (float*)d_out;

  unsigned short* wsb = (unsigned short*)d_ws;
  unsigned short* xb  = wsb;                 // 4M (reused as ao after qkv_gemm)
  unsigned short* wqb = wsb + XEL;           // 4 x 1M weights
  unsigned short* wob = wsb + XEL + 3 * WEL;
  unsigned short* qn  = wsb + XEL + 4 * WEL; // 4M
  unsigned short* kn  = qn + XEL;            // 4M
  unsigned short* vt  = qn + 2 * XEL;        // 4M, transposed + key-permuted
  unsigned short* b16 = qn + 3 * XEL;        // 8M f16 bias cache (ws ~59MB total)
  unsigned short* ao  = xb;                  // alias: xb dead after qkv_gemm

  dim3 blk(256, 1, 1);

  cvt_kernel<<<dim3((unsigned)(TOTEL / (256 * 8)), 1, 1), blk, 0, stream>>>(
      x, bias, Wq, Wk, Wv, Wo, wsb, b16);

  qkv_gemm<<<dim3(M_ROWS / 128, 24, 1), blk, 0, stream>>>(
      xb, wqb, bq, bk, bv, qg, qb, kg, kb, qn, vt);

  attn_kernel<<<dim3(N_B * 16 * (N_SEQ / 128), 1, 1), dim3(512, 1, 1), 0, stream>>>(
      qn, kn, vt, b16, ao);

  out_gemm<<<dim3(M_ROWS / 128, D_MODEL / 128, 1), blk, 0, stream>>>(ao, wob, bo, out);
}

// Round 8
// 235.849 us; speedup vs baseline: 1.1125x; 1.1125x over previous
//
#include <hip/hip_runtime.h>
#include <hip/hip_bf16.h>
#include <hip/hip_fp16.h>

#define D_MODEL 1024
#define N_SEQ   2048
#define N_B     2
#define M_ROWS  (N_B * N_SEQ)   // 4096

typedef __attribute__((ext_vector_type(8))) short bf16x8;
typedef __attribute__((ext_vector_type(4))) float f32x4;

typedef const __attribute__((address_space(1))) unsigned int gu32_t;
typedef __attribute__((address_space(3))) unsigned int lu32_t;

__device__ __forceinline__ void gload16(const void* g, void* l) {
  // async global->LDS, 16B per lane; LDS dest = wave-uniform base + lane*16
  __builtin_amdgcn_global_load_lds((gu32_t*)g, (lu32_t*)l, 16, 0, 0);
}

__device__ inline unsigned short f2bf(float f) {
  union { float f; unsigned int u; } v; v.f = f;
  unsigned int r = (v.u + 0x7FFFu + ((v.u >> 16) & 1u)) >> 16;
  return (unsigned short)r;
}

// packed f32x2 -> bf16x2 (RNE); no builtin on gfx950, per learn_hip m240
__device__ __forceinline__ unsigned int cvt_pk_bf16(float a, float b) {
  unsigned int r;
  asm("v_cvt_pk_bf16_f32 %0, %1, %2" : "=v"(r) : "v"(a), "v"(b));
  return r;
}

__device__ __forceinline__ float exp2fast(float x) {
#if __has_builtin(__builtin_amdgcn_exp2f)
  return __builtin_amdgcn_exp2f(x);
#else
  return __expf(x * 0.69314718056f);
#endif
}

// counted vmcnt wait (T4): never drain to 0 in the main loop
#define WAITV(N) asm volatile("s_waitcnt vmcnt(" #N ")" ::: "memory")

// Bank-conflict swizzle for 64-col (128B-row) LDS tiles:
// logical 16B-chunk k of row r lives at physical chunk k ^ (r & 7).
__device__ __forceinline__ int lds_off(int row, int col /*ushort idx*/) {
  return row * 64 + (((col >> 3) ^ (row & 7)) << 3) + (col & 7);
}

// Stage a ROWS x 64-ushort tile global->LDS with the swizzle applied on the
// global-source side (LDS destination must stay linear for global_load_lds).
template<int ROWS, int NTHR = 256>
__device__ __forceinline__ void stage_tile(const unsigned short* gbase, size_t gstride,
                                           unsigned short* lds, int tid) {
  const int wave = tid >> 6;
#pragma unroll
  for (int rnd = 0; rnd < ROWS * 8 / NTHR; ++rnd) {
    int c = rnd * NTHR + tid;
    int row = c >> 3, pc = c & 7;
    int gcol = ((pc ^ (row & 7)) << 3);
    gload16(gbase + (size_t)row * gstride + gcol,
            lds + (size_t)(rnd * NTHR + wave * 64) * 8);
  }
}

constexpr size_t XEL = (size_t)M_ROWS * D_MODEL;     // 4194304
constexpr size_t WEL = (size_t)D_MODEL * D_MODEL;    // 1048576
constexpr size_t BEL = (size_t)N_B * N_SEQ * N_SEQ;  // 8388608 (attn bias)
constexpr size_t TOTEL = XEL + 4 * WEL + BEL;        // 16777216

// ---------------------------------------------------------------------------
// fp32 -> bf16 convert for [x (4M) | Wq | Wk | Wv | Wo (1M each)] -> dst,
// plus fp32 -> f16 for attn bias (8M) -> dstB (f16 e5m10: |err| ~2^-11 rel).
// ---------------------------------------------------------------------------
__launch_bounds__(256)
__global__ void cvt_kernel(const float* __restrict__ x, const float* __restrict__ bias,
                           const float* __restrict__ wq, const float* __restrict__ wk,
                           const float* __restrict__ wv, const float* __restrict__ wo,
                           unsigned short* __restrict__ dst,
                           unsigned short* __restrict__ dstB) {
  size_t i = ((size_t)blockIdx.x * 256 + threadIdx.x) * 8;
  if (i >= TOTEL) return;
  if (i >= XEL + 4 * WEL) {
    size_t off = i - (XEL + 4 * WEL);
    float4 f0 = *(const float4*)(bias + off);
    float4 f1 = *(const float4*)(bias + off + 4);
    __half t[8] = { __float2half(f0.x), __float2half(f0.y), __float2half(f0.z),
                    __float2half(f0.w), __float2half(f1.x), __float2half(f1.y),
                    __float2half(f1.z), __float2half(f1.w) };
    *(uint4*)(dstB + off) = *(const uint4*)t;
    return;
  }
  const float* s; size_t off = i;
  if (off < XEL)                { s = x; }
  else if (off < XEL + WEL)     { s = wq; off -= XEL; }
  else if (off < XEL + 2*WEL)   { s = wk; off -= XEL + WEL; }
  else if (off < XEL + 3*WEL)   { s = wv; off -= XEL + 2*WEL; }
  else                          { s = wo; off -= XEL + 3*WEL; }
  float4 f0 = *(const float4*)(s + off);
  float4 f1 = *(const float4*)(s + off + 4);
  unsigned short t[8] = { f2bf(f0.x), f2bf(f0.y), f2bf(f0.z), f2bf(f0.w),
                          f2bf(f1.x), f2bf(f1.y), f2bf(f1.z), f2bf(f1.w) };
  *(uint4*)(dst + i) = *(const uint4*)t;
}

// ---------------------------------------------------------------------------
// m97-style 128x128 bf16 mainloop, swizzled LDS: C = A * Bw^T
// ---------------------------------------------------------------------------
__device__ __forceinline__ void mainloop128(const unsigned short* __restrict__ A,
                                            const unsigned short* __restrict__ Bw,
                                            int m0, int e0,
                                            unsigned short* As, unsigned short* Bs,
                                            f32x4 (&acc)[4][4]) {
  const int tid  = threadIdx.x;
  const int wave = tid >> 6, lane = tid & 63;
  const int l16 = lane & 15, quad = lane >> 4;
  const int wr = wave >> 1, wc = wave & 1;

  for (int kt = 0; kt < D_MODEL / 64; ++kt) {
    const int k0 = kt * 64;
    stage_tile<128>(A + (size_t)m0 * D_MODEL + k0, D_MODEL, As, tid);
    stage_tile<128>(Bw + (size_t)e0 * D_MODEL + k0, D_MODEL, Bs, tid);
    __syncthreads();
#pragma unroll
    for (int ks = 0; ks < 2; ++ks) {
      bf16x8 af[4], bfr[4];
#pragma unroll
      for (int mi = 0; mi < 4; ++mi)
        af[mi] = *(const bf16x8*)(As + lds_off(wr * 64 + mi * 16 + l16, ks * 32 + quad * 8));
#pragma unroll
      for (int ci = 0; ci < 4; ++ci)
        bfr[ci] = *(const bf16x8*)(Bs + lds_off(wc * 64 + ci * 16 + l16, ks * 32 + quad * 8));
#pragma unroll
      for (int mi = 0; mi < 4; ++mi)
#pragma unroll
        for (int ci = 0; ci < 4; ++ci)
          acc[mi][ci] = __builtin_amdgcn_mfma_f32_16x16x32_bf16(af[mi], bfr[ci], acc[mi][ci], 0, 0, 0);
    }
    __syncthreads();
  }
}

// ---------------------------------------------------------------------------
// Fused Q/K/V projection. grid (32, 24): by -> {mat = by>>3, e0 = (by&7)*128}.
// mat 0 (q): LN epilogue with 0.125*log2e softmax/exp2 scale folded in.
// mat 1 (k): LN epilogue.
// mat 2 (v): V stored TRANSPOSED per (b,h), keys sigma-permuted within each
//            32-block so attn's in-register P^T fragment lines up with V.
// ---------------------------------------------------------------------------
__launch_bounds__(256)
__global__ void qkv_gemm(const unsigned short* __restrict__ xb,
                         const unsigned short* __restrict__ wb,   // wq|wk|wv bf16
                         const float* __restrict__ bq, const float* __restrict__ bk,
                         const float* __restrict__ bv,
                         const float* __restrict__ qg, const float* __restrict__ qbeta,
                         const float* __restrict__ kg, const float* __restrict__ kbeta,
                         unsigned short* __restrict__ qkout,      // qn | kn
                         unsigned short* __restrict__ vt) {
  __shared__ unsigned short As[128 * 64];
  __shared__ unsigned short Bs[128 * 64];
  const int m0  = blockIdx.x * 128;
  const int by  = blockIdx.y;
  const int mat = by >> 3;
  const int e0  = (by & 7) * 128;
  const unsigned short* Bw = wb + (size_t)mat * WEL;

  f32x4 acc[4][4];
#pragma unroll
  for (int mi = 0; mi < 4; ++mi)
#pragma unroll
    for (int ci = 0; ci < 4; ++ci) acc[mi][ci] = f32x4{0.f, 0.f, 0.f, 0.f};

  mainloop128(xb, Bw, m0, e0, As, Bs, acc);

  const int lane = threadIdx.x & 63, wave = threadIdx.x >> 6;
  const int l16 = lane & 15, quad = lane >> 4;
  const int wr = wave >> 1, wc = wave & 1;
  const int colbase = e0 + wc * 64;          // multiple of 64 -> one head per wave

  const float* bias = (mat == 0) ? bq : ((mat == 1) ? bk : bv);
  float bcol[4];
#pragma unroll
  for (int ci = 0; ci < 4; ++ci) bcol[ci] = bias[colbase + ci * 16 + l16];
#pragma unroll
  for (int mi = 0; mi < 4; ++mi)
#pragma unroll
    for (int ci = 0; ci < 4; ++ci)
#pragma unroll
      for (int r = 0; r < 4; ++r) acc[mi][ci][r] += bcol[ci];

  if (mat < 2) {
    const float* gamma = (mat == 0) ? qg : kg;
    const float* beta  = (mat == 0) ? qbeta : kbeta;
    // fold softmax scale AND log2(e) (attn uses exp2) into q
    const float sc = (mat == 0) ? 0.18033688011112042f : 1.0f;  // 0.125*log2e
    float g4[4], bt4[4];
#pragma unroll
    for (int ci = 0; ci < 4; ++ci) {
      g4[ci] = gamma[ci * 16 + l16] * sc;
      bt4[ci] = beta[ci * 16 + l16] * sc;
    }
#pragma unroll
    for (int mi = 0; mi < 4; ++mi)
#pragma unroll
      for (int r = 0; r < 4; ++r) {
        float s = acc[mi][0][r] + acc[mi][1][r] + acc[mi][2][r] + acc[mi][3][r];
        s += __shfl_xor(s, 1); s += __shfl_xor(s, 2);
        s += __shfl_xor(s, 4); s += __shfl_xor(s, 8);
        float mean = s * (1.f / 64.f);
        float d0 = acc[mi][0][r] - mean, d1 = acc[mi][1][r] - mean;
        float d2 = acc[mi][2][r] - mean, d3 = acc[mi][3][r] - mean;
        float q = d0 * d0 + d1 * d1 + d2 * d2 + d3 * d3;
        q += __shfl_xor(q, 1); q += __shfl_xor(q, 2);
        q += __shfl_xor(q, 4); q += __shfl_xor(q, 8);
        float rs = rsqrtf(q * (1.f / 64.f) + 1e-6f);
        acc[mi][0][r] = d0 * rs * g4[0] + bt4[0];
        acc[mi][1][r] = d1 * rs * g4[1] + bt4[1];
        acc[mi][2][r] = d2 * rs * g4[2] + bt4[2];
        acc[mi][3][r] = d3 * rs * g4[3] + bt4[3];
      }
    unsigned short* out = qkout + (size_t)mat * XEL;
#pragma unroll
    for (int mi = 0; mi < 4; ++mi)
#pragma unroll
      for (int ci = 0; ci < 4; ++ci) {
        int col = colbase + ci * 16 + l16;
#pragma unroll
        for (int r = 0; r < 4; ++r) {
          int row = m0 + wr * 64 + mi * 16 + quad * 4 + r;
          out[(size_t)row * D_MODEL + col] = f2bf(acc[mi][ci][r]);
        }
      }
  } else {
    // V transpose via wave-private LDS scratch (col-swizzled), then each lane
    // stores one full d-row (128B) as 8x dwordx4 -> coalesced.
    // Token index within 64 is sigma-permuted: logical t = 16*half+4*q+r
    // stored at phys = 8*q + 4*half + r (within its 32-block), matching the
    // attention kernel's in-register P^T bf16x8 fragment order.
    unsigned short* scr = ((wave < 2) ? As : Bs) + (size_t)(wave & 1) * 4096;
#pragma unroll
    for (int ci = 0; ci < 4; ++ci) {
      int dl = ci * 16 + l16;
      int sw = (dl & 3) * 16;
#pragma unroll
      for (int mi = 0; mi < 4; ++mi)
#pragma unroll
        for (int r = 0; r < 4; ++r) {
          // logical token t = mi*16 + quad*4 + r  (half = mi&1, block = mi>>1)
          int np = ((mi >> 1) << 5) + (quad << 3) + ((mi & 1) << 2) + r;
          scr[dl * 64 + (np ^ sw)] = f2bf(acc[mi][ci][r]);
        }
    }
    __builtin_amdgcn_wave_barrier();
    int row0 = m0 + wr * 64;                 // token base of this wave's tile
    int b = row0 >> 11, nb = row0 & 2047;
    int h = colbase >> 6;
    int dl = lane;                           // this lane's d within the head
    unsigned short* gdst = vt + ((size_t)((b * 16 + h) * 64 + dl) * N_SEQ + nb);
    const unsigned short* srow = scr + dl * 64;
    int sw = (dl & 3) * 16;
#pragma unroll
    for (int j = 0; j < 8; ++j) {
      uint4 vv = *(const uint4*)(srow + ((j * 8) ^ sw));
      *(uint4*)(gdst + j * 8) = vv;
    }
  }
}

// ---------------------------------------------------------------------------
// Output projection: fp32 out = ao * Wo^T + bo. grid (32, 8).
// ---------------------------------------------------------------------------
__launch_bounds__(256)
__global__ void out_gemm(const unsigned short* __restrict__ ao,
                         const unsigned short* __restrict__ wob,
                         const float* __restrict__ bo,
                         float* __restrict__ out) {
  __shared__ unsigned short As[128 * 64];
  __shared__ unsigned short Bs[128 * 64];
  const int m0 = blockIdx.x * 128;
  const int e0 = blockIdx.y * 128;

  f32x4 acc[4][4];
#pragma unroll
  for (int mi = 0; mi < 4; ++mi)
#pragma unroll
    for (int ci = 0; ci < 4; ++ci) acc[mi][ci] = f32x4{0.f, 0.f, 0.f, 0.f};

  mainloop128(ao, wob, m0, e0, As, Bs, acc);

  const int lane = threadIdx.x & 63, wave = threadIdx.x >> 6;
  const int l16 = lane & 15, quad = lane >> 4;
  const int wr = wave >> 1, wc = wave & 1;
  float bcol[4];
#pragma unroll
  for (int ci = 0; ci < 4; ++ci) bcol[ci] = bo[e0 + wc * 64 + ci * 16 + l16];
#pragma unroll
  for (int mi = 0; mi < 4; ++mi)
#pragma unroll
    for (int ci = 0; ci < 4; ++ci) {
      int col = e0 + wc * 64 + ci * 16 + l16;
#pragma unroll
      for (int r = 0; r < 4; ++r) {
        int row = m0 + wr * 64 + mi * 16 + quad * 4 + r;
        out[(size_t)row * D_MODEL + col] = acc[mi][ci][r] + bcol[ci];
      }
    }
}

// ---------------------------------------------------------------------------
// Flash attention, swapped-operand QK^T, 8 waves / 512 threads per block.
// Wave pair (2p, 2p+1): wave 2p keys [0,32), wave 2p+1 keys [32,64) of the
// shared q-rows [p*32, p*32+32).
// R8: bias joins the DMA stream. The f16 bias tile (128x64 = 16KB, same
// geometry as the Q tile) is staged via global_load_lds at distance 1 into a
// depth-2 LDS buffer; the per-iteration bias-VMEM stall (scattered 8B loads
// retired right before exp with only QK-phase cover) becomes a DMA with one
// FULL iteration of cover. K/V drop to depth-2 with counted waits.
// LDS 64KB: K 2x8K | V 2x8K | bias 2x16K. VGPR discipline: bias regs/pointers
// die; __launch_bounds__(512,4) pins <=64 VGPR (pool ~256/SIMD: 64 VGPR is
// the 2-block boundary, learned R3-R7).
// Ledger/iter: issue [K,V kt+1 (2), bias kt+1 (2)]; top WAITV(4) retires
// bias kt; post-PV WAITV(2) retires K/V kt+1; barrier never drains.
// ---------------------------------------------------------------------------
__launch_bounds__(512, 4)
__global__ void attn_kernel(const unsigned short* __restrict__ Q,
                            const unsigned short* __restrict__ Kn,
                            const unsigned short* __restrict__ Vt,
                            const unsigned short* __restrict__ bias16,  // f16
                            unsigned short* __restrict__ Out) {
  __shared__ unsigned short smem[32768];     // 64KB
  // K bufs:    smem + i*4096       (i=0,1)  [0, 8192)
  // V bufs:    smem + 8192 + i*4096          [8192, 16384)
  // bias bufs: smem + 16384 + i*8192         [16384, 32768)

  const int tid  = threadIdx.x;
  const int wave = tid >> 6, lane = tid & 63;
  const int quad = lane >> 4, l16 = lane & 15;
  const int pairId = wave >> 1;              // 4 pairs x 32 q-rows
  const int kh = wave & 1;                   // key half of the 64-key tile
  const int bidx = blockIdx.x;
  const int qt = bidx & 15;                  // 16 q-tiles of 128
  const int h  = (bidx >> 4) & 15;
  const int b  = bidx >> 8;
  const int q0 = qt * 128;
  const size_t base  = (size_t)b * N_SEQ * D_MODEL + (size_t)h * 64;
  const unsigned short* vtb = Vt + (size_t)(b * 16 + h) * 64 * N_SEQ;
  const unsigned short* bbase = bias16 + ((size_t)b * N_SEQ + q0) * N_SEQ;
  const int bcol0 = kh * 32 + quad * 4;      // this wave's key columns

  // ---- prologue phase 1: Q through LDS (overlays K-bufs), to regs ----
  stage_tile<128, 512>(Q + base + (size_t)q0 * D_MODEL, D_MODEL, smem, tid);
  __syncthreads();                           // Q DMA landed (vmcnt0) + barrier

  bf16x8 aq[2][2];                           // [mi][ks] — shared by the pair
#pragma unroll
  for (int mi = 0; mi < 2; ++mi)
#pragma unroll
    for (int ks = 0; ks < 2; ++ks)
      aq[mi][ks] = *(const bf16x8*)(smem + lds_off(pairId * 32 + mi * 16 + l16, ks * 32 + quad * 8));
  __syncthreads();                           // all waves read Q; safe to reuse

  // ---- prologue phase 2: stage K/V/bias tile 0, drain once ----
  stage_tile<64, 512>(Kn + base, D_MODEL, smem, tid);
  stage_tile<64, 512>(vtb, N_SEQ, smem + 8192, tid);
  stage_tile<128, 512>(bbase, N_SEQ, smem + 16384, tid);

  WAITV(0);
  __builtin_amdgcn_s_barrier();
  __builtin_amdgcn_sched_barrier(0);

  f32x4 o[2][4];                             // O^T partial: d = cd*16+quad*4+r, q = l16
#pragma unroll
  for (int mi = 0; mi < 2; ++mi)
#pragma unroll
    for (int cd = 0; cd < 4; ++cd) o[mi][cd] = f32x4{0.f, 0.f, 0.f, 0.f};
  float lsum[2] = {0.f, 0.f};
  constexpr float LOG2E = 1.44269504088896340736f;

  constexpr int NT = N_SEQ / 64;
  for (int kt = 0; kt < NT; ++kt) {
    const int cur = kt & 1;
    unsigned short* Kcur = smem + cur * 4096;
    unsigned short* Vcur = smem + 8192 + cur * 4096;
    const unsigned short* Bcur = smem + 16384 + cur * 8192;

    if (kt + 1 < NT) {
      const int nb = cur ^ 1;
      // K/V first, bias second (issue order = retirement order for WAITV)
      stage_tile<64, 512>(Kn + base + (size_t)(kt + 1) * 64 * D_MODEL, D_MODEL,
                          smem + nb * 4096, tid);
      stage_tile<64, 512>(vtb + (kt + 1) * 64, N_SEQ,
                          smem + 8192 + nb * 4096, tid);
      stage_tile<128, 512>(bbase + (kt + 1) * 64, N_SEQ,
                           smem + 16384 + nb * 8192, tid);
      // retire bias kt (staged one full iteration ago); keep
      // [K/V kt+1 (2), bias kt+1 (2)] in flight
      WAITV(4);
    } else {
      WAITV(0);                              // last tile: everything landed
    }

    // bias tile kt -> regs early; lgkm latency hides under the QK MFMAs
    uint2 breg[2][2];
#pragma unroll
    for (int mi = 0; mi < 2; ++mi)
#pragma unroll
      for (int cl = 0; cl < 2; ++cl)
        breg[mi][cl] = *(const uint2*)(Bcur +
            lds_off(pairId * 32 + mi * 16 + l16, bcol0 + cl * 16));

    // S^T = K Q^T for this wave's 32 keys (q pre-scaled by 0.125*log2e)
    f32x4 sfT[2][2];                         // [mi][cl]: key = kh*32+cl*16+quad*4+r, q = l16
#pragma unroll
    for (int cl = 0; cl < 2; ++cl) {
      const int c = kh * 2 + cl;
      bf16x8 k0 = *(const bf16x8*)(Kcur + lds_off(c * 16 + l16, quad * 8));
      bf16x8 k1 = *(const bf16x8*)(Kcur + lds_off(c * 16 + l16, 32 + quad * 8));
      __builtin_amdgcn_s_setprio(1);
#pragma unroll
      for (int mi = 0; mi < 2; ++mi) {
        f32x4 z = f32x4{0.f, 0.f, 0.f, 0.f};
        z = __builtin_amdgcn_mfma_f32_16x16x32_bf16(k0, aq[mi][0], z, 0, 0, 0);
        sfT[mi][cl] = __builtin_amdgcn_mfma_f32_16x16x32_bf16(k1, aq[mi][1], z, 0, 0, 0);
      }
      __builtin_amdgcn_s_setprio(0);
    }

    // p = 2^(sT + bias*log2e); f16 bias unpacked via v_cvt_f32_f16.
    // paf k-slot order matches the sigma-permuted Vt layout.
    union PafU { unsigned int w[4]; bf16x8 v; };
    PafU paf[2];
#pragma unroll
    for (int mi = 0; mi < 2; ++mi)
#pragma unroll
      for (int cl = 0; cl < 2; ++cl) {
        uint2 bw = breg[mi][cl];
        float2 fa = __half22float2(*(const __half2*)&bw.x);
        float2 fb = __half22float2(*(const __half2*)&bw.y);
        float p0 = exp2fast(fmaf(fa.x, LOG2E, sfT[mi][cl][0]));
        float p1 = exp2fast(fmaf(fa.y, LOG2E, sfT[mi][cl][1]));
        float p2 = exp2fast(fmaf(fb.x, LOG2E, sfT[mi][cl][2]));
        float p3 = exp2fast(fmaf(fb.y, LOG2E, sfT[mi][cl][3]));
        lsum[mi] += (p0 + p1) + (p2 + p3);
        paf[mi].w[cl * 2]     = cvt_pk_bf16(p0, p1);
        paf[mi].w[cl * 2 + 1] = cvt_pk_bf16(p2, p3);
      }

    // O^T += V^T P^T over this wave's 32 keys (V frags reused across both mi)
    {
      bf16x8 bv[4];
#pragma unroll
      for (int cd = 0; cd < 4; ++cd)
        bv[cd] = *(const bf16x8*)(Vcur + lds_off(cd * 16 + l16, kh * 32 + quad * 8));
      __builtin_amdgcn_s_setprio(1);
#pragma unroll
      for (int mi = 0; mi < 2; ++mi)
#pragma unroll
        for (int cd = 0; cd < 4; ++cd)
          o[mi][cd] = __builtin_amdgcn_mfma_f32_16x16x32_bf16(bv[cd], paf[mi].v, o[mi][cd], 0, 0, 0);
      __builtin_amdgcn_s_setprio(0);
    }

    // counted wait: guarantee K/V kt+1 (issued this iter, top) landed; leave
    // bias kt+1 (2) in flight; raw barrier (no vmcnt(0) drain)
    if (kt + 1 < NT) {
      WAITV(2);
      __builtin_amdgcn_s_barrier();
      __builtin_amdgcn_sched_barrier(0);
    }
  }

  // drain any stragglers before reusing LDS as reduction scratch
  WAITV(0);
  __syncthreads();

  // ---- pair reduction: odd wave dumps partial O + lsum to (dead) LDS ----
  float* red = (float*)smem;                 // need 8704 floats = 34816B < 64KB
  float* slot = red + (size_t)(pairId * 64 + lane) * 34;
  if (kh) {
#pragma unroll
    for (int mi = 0; mi < 2; ++mi)
#pragma unroll
      for (int cd = 0; cd < 4; ++cd)
#pragma unroll
        for (int r = 0; r < 4; ++r)
          slot[mi * 16 + cd * 4 + r] = o[mi][cd][r];
    slot[32] = lsum[0];
    slot[33] = lsum[1];
  }
  __syncthreads();
  if (!kh) {
#pragma unroll
    for (int mi = 0; mi < 2; ++mi)
#pragma unroll
      for (int cd = 0; cd < 4; ++cd)
#pragma unroll
        for (int r = 0; r < 4; ++r)
          o[mi][cd][r] += slot[mi * 16 + cd * 4 + r];
    lsum[0] += slot[32];
    lsum[1] += slot[33];

    // normalize: lsum and O^T columns are both indexed by q = l16 -> lane-local
#pragma unroll
    for (int mi = 0; mi < 2; ++mi) {
      float l = lsum[mi];
      l += __shfl_xor(l, 16);
      l += __shfl_xor(l, 32);
      float inv = 1.0f / l;
      size_t row = (size_t)b * N_SEQ + q0 + pairId * 32 + mi * 16 + l16;
#pragma unroll
      for (int cd = 0; cd < 4; ++cd) {
        uint2 vv;
        vv.x = cvt_pk_bf16(o[mi][cd][0] * inv, o[mi][cd][1] * inv);
        vv.y = cvt_pk_bf16(o[mi][cd][2] * inv, o[mi][cd][3] * inv);
        *(uint2*)(Out + row * D_MODEL + h * 64 + cd * 16 + quad * 4) = vv;
      }
    }
  }
}

extern "C" void kernel_launch(void* const* d_in, const int* in_sizes, int n_in,
                              void* d_out, int out_size, void* d_ws, size_t ws_size,
                              hipStream_t stream) {
  const float* x    = (const float*)d_in[0];
  const float* bias = (const float*)d_in[1];
  const float* Wq = (const float*)d_in[2];  const float* bq = (const float*)d_in[3];
  const float* Wk = (const float*)d_in[4];  const float* bk = (const float*)d_in[5];
  const float* Wv = (const float*)d_in[6];  const float* bv = (const float*)d_in[7];
  const float* Wo = (const float*)d_in[8];  const float* bo = (const float*)d_in[9];
  const float* qg = (const float*)d_in[10]; const float* qb = (const float*)d_in[11];
  const float* kg = (const float*)d_in[12]; const float* kb = (const float*)d_in[13];
  float* out = (float*)d_out;

  unsigned short* wsb = (unsigned short*)d_ws;
  unsigned short* xb  = wsb;                 // 4M (reused as ao after qkv_gemm)
  unsigned short* wqb = wsb + XEL;           // 4 x 1M weights
  unsigned short* wob = wsb + XEL + 3 * WEL;
  unsigned short* qn  = wsb + XEL + 4 * WEL; // 4M
  unsigned short* kn  = qn + XEL;            // 4M
  unsigned short* vt  = qn + 2 * XEL;        // 4M, transposed + key-permuted
  unsigned short* b16 = qn + 3 * XEL;        // 8M f16 bias cache (ws ~59MB total)
  unsigned short* ao  = xb;                  // alias: xb dead after qkv_gemm

  dim3 blk(256, 1, 1);

  cvt_kernel<<<dim3((unsigned)(TOTEL / (256 * 8)), 1, 1), blk, 0, stream>>>(
      x, bias, Wq, Wk, Wv, Wo, wsb, b16);

  qkv_gemm<<<dim3(M_ROWS / 128, 24, 1), blk, 0, stream>>>(
      xb, wqb, bq, bk, bv, qg, qb, kg, kb, qn, vt);

  attn_kernel<<<dim3(N_B * 16 * (N_SEQ / 128), 1, 1), dim3(512, 1, 1), 0, stream>>>(
      qn, kn, vt, b16, ao);

  out_gemm<<<dim3(M_ROWS / 128, D_MODEL / 128, 1), blk, 0, stream>>>(ao, wob, bo, out);
}

// Round 9
// 234.884 us; speedup vs baseline: 1.1170x; 1.0041x over previous
//
#include <hip/hip_runtime.h>
#include <hip/hip_bf16.h>
#include <hip/hip_fp16.h>

#define D_MODEL 1024
#define N_SEQ   2048
#define N_B     2
#define M_ROWS  (N_B * N_SEQ)   // 4096

typedef __attribute__((ext_vector_type(8))) short bf16x8;
typedef __attribute__((ext_vector_type(4))) float f32x4;

typedef const __attribute__((address_space(1))) unsigned int gu32_t;
typedef __attribute__((address_space(3))) unsigned int lu32_t;

__device__ __forceinline__ void gload16(const void* g, void* l) {
  // async global->LDS, 16B per lane; LDS dest = wave-uniform base + lane*16
  __builtin_amdgcn_global_load_lds((gu32_t*)g, (lu32_t*)l, 16, 0, 0);
}

__device__ inline unsigned short f2bf(float f) {
  union { float f; unsigned int u; } v; v.f = f;
  unsigned int r = (v.u + 0x7FFFu + ((v.u >> 16) & 1u)) >> 16;
  return (unsigned short)r;
}

// packed f32x2 -> bf16x2 (RNE); no builtin on gfx950, per learn_hip m240
__device__ __forceinline__ unsigned int cvt_pk_bf16(float a, float b) {
  unsigned int r;
  asm("v_cvt_pk_bf16_f32 %0, %1, %2" : "=v"(r) : "v"(a), "v"(b));
  return r;
}

__device__ __forceinline__ float exp2fast(float x) {
#if __has_builtin(__builtin_amdgcn_exp2f)
  return __builtin_amdgcn_exp2f(x);
#else
  return __expf(x * 0.69314718056f);
#endif
}

// counted vmcnt wait (T4): never drain to 0 in the main loop
#define WAITV(N) asm volatile("s_waitcnt vmcnt(" #N ")" ::: "memory")

// Bank-conflict swizzle for 64-col (128B-row) LDS tiles, 16B granularity:
// logical 16B-chunk k of row r lives at physical chunk k ^ (r & 7).
__device__ __forceinline__ int lds_off(int row, int col /*ushort idx*/) {
  return row * 64 + (((col >> 3) ^ (row & 7)) << 3) + (col & 7);
}

// Stage a ROWS x 64-ushort tile global->LDS with the swizzle applied on the
// global-source side (LDS destination must stay linear for global_load_lds).
template<int ROWS, int NTHR = 256>
__device__ __forceinline__ void stage_tile(const unsigned short* gbase, size_t gstride,
                                           unsigned short* lds, int tid) {
  const int wave = tid >> 6;
#pragma unroll
  for (int rnd = 0; rnd < ROWS * 8 / NTHR; ++rnd) {
    int c = rnd * NTHR + tid;
    int row = c >> 3, pc = c & 7;
    int gcol = ((pc ^ (row & 7)) << 3);
    gload16(gbase + (size_t)row * gstride + gcol,
            lds + (size_t)(rnd * NTHR + wave * 64) * 8);
  }
}

// Plain linear stage for the PRE-PERMUTED bias tile (128 rows x 64 ushorts):
// the 8B-granular swizzle is baked into the b16 buffer by cvt_kernel, so the
// DMA is a straight copy (2 rounds at 512 threads).
__device__ __forceinline__ void stage_bias(const unsigned short* gbase,
                                           unsigned short* lds, int tid) {
  const int wave = tid >> 6;
#pragma unroll
  for (int rnd = 0; rnd < 2; ++rnd) {
    int c = rnd * 512 + tid;
    int row = c >> 3, pc = c & 7;
    gload16(gbase + (size_t)row * N_SEQ + pc * 8,
            lds + (size_t)(rnd * 512 + wave * 64) * 8);
  }
}

constexpr size_t XEL = (size_t)M_ROWS * D_MODEL;     // 4194304
constexpr size_t WEL = (size_t)D_MODEL * D_MODEL;    // 1048576
constexpr size_t BEL = (size_t)N_B * N_SEQ * N_SEQ;  // 8388608 (attn bias)
constexpr size_t TOTEL = XEL + 4 * WEL + BEL;        // 16777216

// ---------------------------------------------------------------------------
// fp32 -> bf16 convert for [x (4M) | Wq | Wk | Wv | Wo (1M each)] -> dst,
// plus bias -> f16 * log2e, PRE-PERMUTED for attn's conflict-free b64 reads:
// within each 64-key tile, 8B unit c8 of row q is stored at c8 ^ (q&15)
// (16B unit j -> j ^ ((q>>1)&7), halves swapped when q&1).
// ---------------------------------------------------------------------------
__launch_bounds__(256)
__global__ void cvt_kernel(const float* __restrict__ x, const float* __restrict__ bias,
                           const float* __restrict__ wq, const float* __restrict__ wk,
                           const float* __restrict__ wv, const float* __restrict__ wo,
                           unsigned short* __restrict__ dst,
                           unsigned short* __restrict__ dstB) {
  size_t i = ((size_t)blockIdx.x * 256 + threadIdx.x) * 8;
  if (i >= TOTEL) return;
  if (i >= XEL + 4 * WEL) {
    size_t off = i - (XEL + 4 * WEL);
    int row = (int)(off >> 11);              // global q-row (b*2048 + q)
    int key = (int)(off & 2047);
    constexpr float LOG2E = 1.44269504088896340736f;
    float4 f0 = *(const float4*)(bias + off);
    float4 f1 = *(const float4*)(bias + off + 4);
    __half t[8] = { __float2half(f0.x * LOG2E), __float2half(f0.y * LOG2E),
                    __float2half(f0.z * LOG2E), __float2half(f0.w * LOG2E),
                    __float2half(f1.x * LOG2E), __float2half(f1.y * LOG2E),
                    __float2half(f1.z * LOG2E), __float2half(f1.w * LOG2E) };
    int j  = (key >> 3) & 7;                 // 16B unit within 64-key tile
    int jp = j ^ ((row >> 1) & 7);
    uint4 v = *(const uint4*)t;
    if (row & 1) { uint4 w; w.x = v.z; w.y = v.w; w.z = v.x; w.w = v.y; v = w; }
    *(uint4*)(dstB + (((size_t)row << 11) + (key & ~63) + jp * 8)) = v;
    return;
  }
  const float* s; size_t off = i;
  if (off < XEL)                { s = x; }
  else if (off < XEL + WEL)     { s = wq; off -= XEL; }
  else if (off < XEL + 2*WEL)   { s = wk; off -= XEL + WEL; }
  else if (off < XEL + 3*WEL)   { s = wv; off -= XEL + 2*WEL; }
  else                          { s = wo; off -= XEL + 3*WEL; }
  float4 f0 = *(const float4*)(s + off);
  float4 f1 = *(const float4*)(s + off + 4);
  unsigned short t[8] = { f2bf(f0.x), f2bf(f0.y), f2bf(f0.z), f2bf(f0.w),
                          f2bf(f1.x), f2bf(f1.y), f2bf(f1.z), f2bf(f1.w) };
  *(uint4*)(dst + i) = *(const uint4*)t;
}

// ---------------------------------------------------------------------------
// m97-style 128x128 bf16 mainloop, swizzled LDS: C = A * Bw^T
// ---------------------------------------------------------------------------
__device__ __forceinline__ void mainloop128(const unsigned short* __restrict__ A,
                                            const unsigned short* __restrict__ Bw,
                                            int m0, int e0,
                                            unsigned short* As, unsigned short* Bs,
                                            f32x4 (&acc)[4][4]) {
  const int tid  = threadIdx.x;
  const int wave = tid >> 6, lane = tid & 63;
  const int l16 = lane & 15, quad = lane >> 4;
  const int wr = wave >> 1, wc = wave & 1;

  for (int kt = 0; kt < D_MODEL / 64; ++kt) {
    const int k0 = kt * 64;
    stage_tile<128>(A + (size_t)m0 * D_MODEL + k0, D_MODEL, As, tid);
    stage_tile<128>(Bw + (size_t)e0 * D_MODEL + k0, D_MODEL, Bs, tid);
    __syncthreads();
#pragma unroll
    for (int ks = 0; ks < 2; ++ks) {
      bf16x8 af[4], bfr[4];
#pragma unroll
      for (int mi = 0; mi < 4; ++mi)
        af[mi] = *(const bf16x8*)(As + lds_off(wr * 64 + mi * 16 + l16, ks * 32 + quad * 8));
#pragma unroll
      for (int ci = 0; ci < 4; ++ci)
        bfr[ci] = *(const bf16x8*)(Bs + lds_off(wc * 64 + ci * 16 + l16, ks * 32 + quad * 8));
#pragma unroll
      for (int mi = 0; mi < 4; ++mi)
#pragma unroll
        for (int ci = 0; ci < 4; ++ci)
          acc[mi][ci] = __builtin_amdgcn_mfma_f32_16x16x32_bf16(af[mi], bfr[ci], acc[mi][ci], 0, 0, 0);
    }
    __syncthreads();
  }
}

// ---------------------------------------------------------------------------
// Fused Q/K/V projection. grid (32, 24): by -> {mat = by>>3, e0 = (by&7)*128}.
// mat 0 (q): LN epilogue with 0.125*log2e softmax/exp2 scale folded in.
// mat 1 (k): LN epilogue.
// mat 2 (v): V stored TRANSPOSED per (b,h), keys sigma-permuted within each
//            32-block so attn's in-register P^T fragment lines up with V.
// ---------------------------------------------------------------------------
__launch_bounds__(256)
__global__ void qkv_gemm(const unsigned short* __restrict__ xb,
                         const unsigned short* __restrict__ wb,   // wq|wk|wv bf16
                         const float* __restrict__ bq, const float* __restrict__ bk,
                         const float* __restrict__ bv,
                         const float* __restrict__ qg, const float* __restrict__ qbeta,
                         const float* __restrict__ kg, const float* __restrict__ kbeta,
                         unsigned short* __restrict__ qkout,      // qn | kn
                         unsigned short* __restrict__ vt) {
  __shared__ unsigned short As[128 * 64];
  __shared__ unsigned short Bs[128 * 64];
  const int m0  = blockIdx.x * 128;
  const int by  = blockIdx.y;
  const int mat = by >> 3;
  const int e0  = (by & 7) * 128;
  const unsigned short* Bw = wb + (size_t)mat * WEL;

  f32x4 acc[4][4];
#pragma unroll
  for (int mi = 0; mi < 4; ++mi)
#pragma unroll
    for (int ci = 0; ci < 4; ++ci) acc[mi][ci] = f32x4{0.f, 0.f, 0.f, 0.f};

  mainloop128(xb, Bw, m0, e0, As, Bs, acc);

  const int lane = threadIdx.x & 63, wave = threadIdx.x >> 6;
  const int l16 = lane & 15, quad = lane >> 4;
  const int wr = wave >> 1, wc = wave & 1;
  const int colbase = e0 + wc * 64;          // multiple of 64 -> one head per wave

  const float* bias = (mat == 0) ? bq : ((mat == 1) ? bk : bv);
  float bcol[4];
#pragma unroll
  for (int ci = 0; ci < 4; ++ci) bcol[ci] = bias[colbase + ci * 16 + l16];
#pragma unroll
  for (int mi = 0; mi < 4; ++mi)
#pragma unroll
    for (int ci = 0; ci < 4; ++ci)
#pragma unroll
      for (int r = 0; r < 4; ++r) acc[mi][ci][r] += bcol[ci];

  if (mat < 2) {
    const float* gamma = (mat == 0) ? qg : kg;
    const float* beta  = (mat == 0) ? qbeta : kbeta;
    // fold softmax scale AND log2(e) (attn uses exp2) into q
    const float sc = (mat == 0) ? 0.18033688011112042f : 1.0f;  // 0.125*log2e
    float g4[4], bt4[4];
#pragma unroll
    for (int ci = 0; ci < 4; ++ci) {
      g4[ci] = gamma[ci * 16 + l16] * sc;
      bt4[ci] = beta[ci * 16 + l16] * sc;
    }
#pragma unroll
    for (int mi = 0; mi < 4; ++mi)
#pragma unroll
      for (int r = 0; r < 4; ++r) {
        float s = acc[mi][0][r] + acc[mi][1][r] + acc[mi][2][r] + acc[mi][3][r];
        s += __shfl_xor(s, 1); s += __shfl_xor(s, 2);
        s += __shfl_xor(s, 4); s += __shfl_xor(s, 8);
        float mean = s * (1.f / 64.f);
        float d0 = acc[mi][0][r] - mean, d1 = acc[mi][1][r] - mean;
        float d2 = acc[mi][2][r] - mean, d3 = acc[mi][3][r] - mean;
        float q = d0 * d0 + d1 * d1 + d2 * d2 + d3 * d3;
        q += __shfl_xor(q, 1); q += __shfl_xor(q, 2);
        q += __shfl_xor(q, 4); q += __shfl_xor(q, 8);
        float rs = rsqrtf(q * (1.f / 64.f) + 1e-6f);
        acc[mi][0][r] = d0 * rs * g4[0] + bt4[0];
        acc[mi][1][r] = d1 * rs * g4[1] + bt4[1];
        acc[mi][2][r] = d2 * rs * g4[2] + bt4[2];
        acc[mi][3][r] = d3 * rs * g4[3] + bt4[3];
      }
    unsigned short* out = qkout + (size_t)mat * XEL;
#pragma unroll
    for (int mi = 0; mi < 4; ++mi)
#pragma unroll
      for (int ci = 0; ci < 4; ++ci) {
        int col = colbase + ci * 16 + l16;
#pragma unroll
        for (int r = 0; r < 4; ++r) {
          int row = m0 + wr * 64 + mi * 16 + quad * 4 + r;
          out[(size_t)row * D_MODEL + col] = f2bf(acc[mi][ci][r]);
        }
      }
  } else {
    // V transpose via wave-private LDS scratch (col-swizzled), then each lane
    // stores one full d-row (128B) as 8x dwordx4 -> coalesced.
    // Token index within 64 is sigma-permuted: logical t = 16*half+4*q+r
    // stored at phys = 8*q + 4*half + r (within its 32-block), matching the
    // attention kernel's in-register P^T bf16x8 fragment order.
    unsigned short* scr = ((wave < 2) ? As : Bs) + (size_t)(wave & 1) * 4096;
#pragma unroll
    for (int ci = 0; ci < 4; ++ci) {
      int dl = ci * 16 + l16;
      int sw = (dl & 3) * 16;
#pragma unroll
      for (int mi = 0; mi < 4; ++mi)
#pragma unroll
        for (int r = 0; r < 4; ++r) {
          // logical token t = mi*16 + quad*4 + r  (half = mi&1, block = mi>>1)
          int np = ((mi >> 1) << 5) + (quad << 3) + ((mi & 1) << 2) + r;
          scr[dl * 64 + (np ^ sw)] = f2bf(acc[mi][ci][r]);
        }
    }
    __builtin_amdgcn_wave_barrier();
    int row0 = m0 + wr * 64;                 // token base of this wave's tile
    int b = row0 >> 11, nb = row0 & 2047;
    int h = colbase >> 6;
    int dl = lane;                           // this lane's d within the head
    unsigned short* gdst = vt + ((size_t)((b * 16 + h) * 64 + dl) * N_SEQ + nb);
    const unsigned short* srow = scr + dl * 64;
    int sw = (dl & 3) * 16;
#pragma unroll
    for (int j = 0; j < 8; ++j) {
      uint4 vv = *(const uint4*)(srow + ((j * 8) ^ sw));
      *(uint4*)(gdst + j * 8) = vv;
    }
  }
}

// ---------------------------------------------------------------------------
// Output projection: fp32 out = ao * Wo^T + bo. grid (32, 8).
// ---------------------------------------------------------------------------
__launch_bounds__(256)
__global__ void out_gemm(const unsigned short* __restrict__ ao,
                         const unsigned short* __restrict__ wob,
                         const float* __restrict__ bo,
                         float* __restrict__ out) {
  __shared__ unsigned short As[128 * 64];
  __shared__ unsigned short Bs[128 * 64];
  const int m0 = blockIdx.x * 128;
  const int e0 = blockIdx.y * 128;

  f32x4 acc[4][4];
#pragma unroll
  for (int mi = 0; mi < 4; ++mi)
#pragma unroll
    for (int ci = 0; ci < 4; ++ci) acc[mi][ci] = f32x4{0.f, 0.f, 0.f, 0.f};

  mainloop128(ao, wob, m0, e0, As, Bs, acc);

  const int lane = threadIdx.x & 63, wave = threadIdx.x >> 6;
  const int l16 = lane & 15, quad = lane >> 4;
  const int wr = wave >> 1, wc = wave & 1;
  float bcol[4];
#pragma unroll
  for (int ci = 0; ci < 4; ++ci) bcol[ci] = bo[e0 + wc * 64 + ci * 16 + l16];
#pragma unroll
  for (int mi = 0; mi < 4; ++mi)
#pragma unroll
    for (int ci = 0; ci < 4; ++ci) {
      int col = e0 + wc * 64 + ci * 16 + l16;
#pragma unroll
      for (int r = 0; r < 4; ++r) {
        int row = m0 + wr * 64 + mi * 16 + quad * 4 + r;
        out[(size_t)row * D_MODEL + col] = acc[mi][ci][r] + bcol[ci];
      }
    }
}

// ---------------------------------------------------------------------------
// Flash attention, swapped-operand QK^T, 8 waves / 512 threads per block.
// Wave pair (2p, 2p+1): wave 2p keys [0,32), wave 2p+1 keys [32,64) of the
// shared q-rows [p*32, p*32+32).
// R9 (on top of R8's bias-DMA pipeline):
//  - bias LDS reads are now CONFLICT-FREE: b16 is pre-permuted at 8B
//    granularity (c8 ^ (q&15)) by cvt_kernel; staged linearly; read at
//    row*64 + ((c8^l16)<<2) -> each 16-lane phase hits all 32 banks once.
//    (R8's 16B-chunk swizzle gave 2-way conflicts on every b64 bias read:
//    SQ_LDS_BANK_CONFLICT 1.05M.)
//  - bias (pre-scaled by log2e in cvt) feeds the QK MFMA as C-INIT:
//    sfT = K q^T + bias*log2e accumulated in-MFMA. Kills 16 v_fma per
//    wave-iter; exp block is pure v_exp_f32.
// LDS 64KB: K 2x8K | V 2x8K | bias 2x16K. __launch_bounds__(512,4) pins
// <=64 VGPR (2-block boundary). Ledger/iter: issue [K,V kt+1, bias kt+1 x2];
// top WAITV(4) retires bias kt; post-PV WAITV(2) retires K/V kt+1.
// ---------------------------------------------------------------------------
__launch_bounds__(512, 4)
__global__ void attn_kernel(const unsigned short* __restrict__ Q,
                            const unsigned short* __restrict__ Kn,
                            const unsigned short* __restrict__ Vt,
                            const unsigned short* __restrict__ bias16,  // f16*log2e, permuted
                            unsigned short* __restrict__ Out) {
  __shared__ unsigned short smem[32768];     // 64KB
  // K bufs:    smem + i*4096       (i=0,1)  [0, 8192)
  // V bufs:    smem + 8192 + i*4096          [8192, 16384)
  // bias bufs: smem + 16384 + i*8192         [16384, 32768)

  const int tid  = threadIdx.x;
  const int wave = tid >> 6, lane = tid & 63;
  const int quad = lane >> 4, l16 = lane & 15;
  const int pairId = wave >> 1;              // 4 pairs x 32 q-rows
  const int kh = wave & 1;                   // key half of the 64-key tile
  const int bidx = blockIdx.x;
  const int qt = bidx & 15;                  // 16 q-tiles of 128
  const int h  = (bidx >> 4) & 15;
  const int b  = bidx >> 8;
  const int q0 = qt * 128;
  const size_t base  = (size_t)b * N_SEQ * D_MODEL + (size_t)h * 64;
  const unsigned short* vtb = Vt + (size_t)(b * 16 + h) * 64 * N_SEQ;
  const unsigned short* bbase = bias16 + ((size_t)b * N_SEQ + q0) * N_SEQ;

  // ---- prologue phase 1: Q through LDS (overlays K-bufs), to regs ----
  stage_tile<128, 512>(Q + base + (size_t)q0 * D_MODEL, D_MODEL, smem, tid);
  __syncthreads();                           // Q DMA landed (vmcnt0) + barrier

  bf16x8 aq[2][2];                           // [mi][ks] — shared by the pair
#pragma unroll
  for (int mi = 0; mi < 2; ++mi)
#pragma unroll
    for (int ks = 0; ks < 2; ++ks)
      aq[mi][ks] = *(const bf16x8*)(smem + lds_off(pairId * 32 + mi * 16 + l16, ks * 32 + quad * 8));
  __syncthreads();                           // all waves read Q; safe to reuse

  // ---- prologue phase 2: stage K/V/bias tile 0, drain once ----
  stage_tile<64, 512>(Kn + base, D_MODEL, smem, tid);
  stage_tile<64, 512>(vtb, N_SEQ, smem + 8192, tid);
  stage_bias(bbase, smem + 16384, tid);

  WAITV(0);
  __builtin_amdgcn_s_barrier();
  __builtin_amdgcn_sched_barrier(0);

  f32x4 o[2][4];                             // O^T partial: d = cd*16+quad*4+r, q = l16
#pragma unroll
  for (int mi = 0; mi < 2; ++mi)
#pragma unroll
    for (int cd = 0; cd < 4; ++cd) o[mi][cd] = f32x4{0.f, 0.f, 0.f, 0.f};
  float lsum[2] = {0.f, 0.f};

  constexpr int NT = N_SEQ / 64;
  for (int kt = 0; kt < NT; ++kt) {
    const int cur = kt & 1;
    unsigned short* Kcur = smem + cur * 4096;
    unsigned short* Vcur = smem + 8192 + cur * 4096;
    const unsigned short* Bcur = smem + 16384 + cur * 8192;

    if (kt + 1 < NT) {
      const int nb = cur ^ 1;
      // K/V first, bias second (issue order = retirement order for WAITV)
      stage_tile<64, 512>(Kn + base + (size_t)(kt + 1) * 64 * D_MODEL, D_MODEL,
                          smem + nb * 4096, tid);
      stage_tile<64, 512>(vtb + (kt + 1) * 64, N_SEQ,
                          smem + 8192 + nb * 4096, tid);
      stage_bias(bbase + (kt + 1) * 64, smem + 16384 + nb * 8192, tid);
      // retire bias kt (staged one full iteration ago); keep
      // [K/V kt+1 (2), bias kt+1 (2)] in flight
      WAITV(4);
    } else {
      WAITV(0);                              // last tile: everything landed
    }

    // bias tile kt -> f32 accumulator-init values (conflict-free b64 reads;
    // c8 = kh*8 + quad + cl*4, phys = row*64 + ((c8^l16)<<2))
    f32x4 zb[2][2];
#pragma unroll
    for (int mi = 0; mi < 2; ++mi)
#pragma unroll
      for (int cl = 0; cl < 2; ++cl) {
        uint2 bw = *(const uint2*)(Bcur + (pairId * 32 + mi * 16 + l16) * 64 +
                                   (((kh * 8 + quad + cl * 4) ^ l16) << 2));
        float2 fa = __half22float2(*(const __half2*)&bw.x);
        float2 fb = __half22float2(*(const __half2*)&bw.y);
        zb[mi][cl] = f32x4{fa.x, fa.y, fb.x, fb.y};
      }

    // S^T = K Q^T + bias*log2e (bias as MFMA C-init; q pre-scaled 0.125*log2e)
    f32x4 sfT[2][2];                         // [mi][cl]: key = kh*32+cl*16+quad*4+r, q = l16
#pragma unroll
    for (int cl = 0; cl < 2; ++cl) {
      const int c = kh * 2 + cl;
      bf16x8 k0 = *(const bf16x8*)(Kcur + lds_off(c * 16 + l16, quad * 8));
      bf16x8 k1 = *(const bf16x8*)(Kcur + lds_off(c * 16 + l16, 32 + quad * 8));
      __builtin_amdgcn_s_setprio(1);
#pragma unroll
      for (int mi = 0; mi < 2; ++mi) {
        f32x4 z = __builtin_amdgcn_mfma_f32_16x16x32_bf16(k0, aq[mi][0], zb[mi][cl], 0, 0, 0);
        sfT[mi][cl] = __builtin_amdgcn_mfma_f32_16x16x32_bf16(k1, aq[mi][1], z, 0, 0, 0);
      }
      __builtin_amdgcn_s_setprio(0);
    }

    // p = 2^sfT; accumulate partial l; pack P^T (k-slot order = sigma-perm Vt)
    union PafU { unsigned int w[4]; bf16x8 v; };
    PafU paf[2];
#pragma unroll
    for (int mi = 0; mi < 2; ++mi)
#pragma unroll
      for (int cl = 0; cl < 2; ++cl) {
        float p0 = exp2fast(sfT[mi][cl][0]);
        float p1 = exp2fast(sfT[mi][cl][1]);
        float p2 = exp2fast(sfT[mi][cl][2]);
        float p3 = exp2fast(sfT[mi][cl][3]);
        lsum[mi] += (p0 + p1) + (p2 + p3);
        paf[mi].w[cl * 2]     = cvt_pk_bf16(p0, p1);
        paf[mi].w[cl * 2 + 1] = cvt_pk_bf16(p2, p3);
      }

    // O^T += V^T P^T over this wave's 32 keys (V frags reused across both mi)
    {
      bf16x8 bv[4];
#pragma unroll
      for (int cd = 0; cd < 4; ++cd)
        bv[cd] = *(const bf16x8*)(Vcur + lds_off(cd * 16 + l16, kh * 32 + quad * 8));
      __builtin_amdgcn_s_setprio(1);
#pragma unroll
      for (int mi = 0; mi < 2; ++mi)
#pragma unroll
        for (int cd = 0; cd < 4; ++cd)
          o[mi][cd] = __builtin_amdgcn_mfma_f32_16x16x32_bf16(bv[cd], paf[mi].v, o[mi][cd], 0, 0, 0);
      __builtin_amdgcn_s_setprio(0);
    }

    // counted wait: guarantee K/V kt+1 (issued this iter, top) landed; leave
    // bias kt+1 (2) in flight; raw barrier (no vmcnt(0) drain)
    if (kt + 1 < NT) {
      WAITV(2);
      __builtin_amdgcn_s_barrier();
      __builtin_amdgcn_sched_barrier(0);
    }
  }

  // drain any stragglers before reusing LDS as reduction scratch
  WAITV(0);
  __syncthreads();

  // ---- pair reduction: odd wave dumps partial O + lsum to (dead) LDS ----
  float* red = (float*)smem;                 // need 8704 floats = 34816B < 64KB
  float* slot = red + (size_t)(pairId * 64 + lane) * 34;
  const int kh2 = wave & 1;
  if (kh2) {
#pragma unroll
    for (int mi = 0; mi < 2; ++mi)
#pragma unroll
      for (int cd = 0; cd < 4; ++cd)
#pragma unroll
        for (int r = 0; r < 4; ++r)
          slot[mi * 16 + cd * 4 + r] = o[mi][cd][r];
    slot[32] = lsum[0];
    slot[33] = lsum[1];
  }
  __syncthreads();
  if (!kh2) {
#pragma unroll
    for (int mi = 0; mi < 2; ++mi)
#pragma unroll
      for (int cd = 0; cd < 4; ++cd)
#pragma unroll
        for (int r = 0; r < 4; ++r)
          o[mi][cd][r] += slot[mi * 16 + cd * 4 + r];
    lsum[0] += slot[32];
    lsum[1] += slot[33];

    // normalize: lsum and O^T columns are both indexed by q = l16 -> lane-local
#pragma unroll
    for (int mi = 0; mi < 2; ++mi) {
      float l = lsum[mi];
      l += __shfl_xor(l, 16);
      l += __shfl_xor(l, 32);
      float inv = 1.0f / l;
      size_t row = (size_t)b * N_SEQ + q0 + pairId * 32 + mi * 16 + l16;
#pragma unroll
      for (int cd = 0; cd < 4; ++cd) {
        uint2 vv;
        vv.x = cvt_pk_bf16(o[mi][cd][0] * inv, o[mi][cd][1] * inv);
        vv.y = cvt_pk_bf16(o[mi][cd][2] * inv, o[mi][cd][3] * inv);
        *(uint2*)(Out + row * D_MODEL + h * 64 + cd * 16 + quad * 4) = vv;
      }
    }
  }
}

extern "C" void kernel_launch(void* const* d_in, const int* in_sizes, int n_in,
                              void* d_out, int out_size, void* d_ws, size_t ws_size,
                              hipStream_t stream) {
  const float* x    = (const float*)d_in[0];
  const float* bias = (const float*)d_in[1];
  const float* Wq = (const float*)d_in[2];  const float* bq = (const float*)d_in[3];
  const float* Wk = (const float*)d_in[4];  const float* bk = (const float*)d_in[5];
  const float* Wv = (const float*)d_in[6];  const float* bv = (const float*)d_in[7];
  const float* Wo = (const float*)d_in[8];  const float* bo = (const float*)d_in[9];
  const float* qg = (const float*)d_in[10]; const float* qb = (const float*)d_in[11];
  const float* kg = (const float*)d_in[12]; const float* kb = (const float*)d_in[13];
  float* out = (float*)d_out;

  unsigned short* wsb = (unsigned short*)d_ws;
  unsigned short* xb  = wsb;                 // 4M (reused as ao after qkv_gemm)
  unsigned short* wqb = wsb + XEL;           // 4 x 1M weights
  unsigned short* wob = wsb + XEL + 3 * WEL;
  unsigned short* qn  = wsb + XEL + 4 * WEL; // 4M
  unsigned short* kn  = qn + XEL;            // 4M
  unsigned short* vt  = qn + 2 * XEL;        // 4M, transposed + key-permuted
  unsigned short* b16 = qn + 3 * XEL;        // 8M f16 bias cache (permuted, *log2e)
  unsigned short* ao  = xb;                  // alias: xb dead after qkv_gemm

  dim3 blk(256, 1, 1);

  cvt_kernel<<<dim3((unsigned)(TOTEL / (256 * 8)), 1, 1), blk, 0, stream>>>(
      x, bias, Wq, Wk, Wv, Wo, wsb, b16);

  qkv_gemm<<<dim3(M_ROWS / 128, 24, 1), blk, 0, stream>>>(
      xb, wqb, bq, bk, bv, qg, qb, kg, kb, qn, vt);

  attn_kernel<<<dim3(N_B * 16 * (N_SEQ / 128), 1, 1), dim3(512, 1, 1), 0, stream>>>(
      qn, kn, vt, b16, ao);

  out_gemm<<<dim3(M_ROWS / 128, D_MODEL / 128, 1), blk, 0, stream>>>(ao, wob, bo, out);
}

// Round 10
// 232.918 us; speedup vs baseline: 1.1265x; 1.0084x over previous
//
#include <hip/hip_runtime.h>
#include <hip/hip_bf16.h>
#include <hip/hip_fp16.h>

#define D_MODEL 1024
#define N_SEQ   2048
#define N_B     2
#define M_ROWS  (N_B * N_SEQ)   // 4096

typedef __attribute__((ext_vector_type(8))) short bf16x8;
typedef __attribute__((ext_vector_type(4))) float f32x4;

typedef const __attribute__((address_space(1))) unsigned int gu32_t;
typedef __attribute__((address_space(3))) unsigned int lu32_t;

__device__ __forceinline__ void gload16(const void* g, void* l) {
  // async global->LDS, 16B per lane; LDS dest = wave-uniform base + lane*16
  __builtin_amdgcn_global_load_lds((gu32_t*)g, (lu32_t*)l, 16, 0, 0);
}

__device__ inline unsigned short f2bf(float f) {
  union { float f; unsigned int u; } v; v.f = f;
  unsigned int r = (v.u + 0x7FFFu + ((v.u >> 16) & 1u)) >> 16;
  return (unsigned short)r;
}

// packed f32x2 -> bf16x2 (RNE); no builtin on gfx950, per learn_hip m240
__device__ __forceinline__ unsigned int cvt_pk_bf16(float a, float b) {
  unsigned int r;
  asm("v_cvt_pk_bf16_f32 %0, %1, %2" : "=v"(r) : "v"(a), "v"(b));
  return r;
}

__device__ __forceinline__ float exp2fast(float x) {
#if __has_builtin(__builtin_amdgcn_exp2f)
  return __builtin_amdgcn_exp2f(x);
#else
  return __expf(x * 0.69314718056f);
#endif
}

// counted vmcnt wait (T4): never drain to 0 in the main loop
#define WAITV(N) asm volatile("s_waitcnt vmcnt(" #N ")" ::: "memory")

// Bank-conflict swizzle for 64-col (128B-row) LDS tiles, 16B granularity:
// logical 16B-chunk k of row r lives at physical chunk k ^ (r & 7).
__device__ __forceinline__ int lds_off(int row, int col /*ushort idx*/) {
  return row * 64 + (((col >> 3) ^ (row & 7)) << 3) + (col & 7);
}

// Stage a ROWS x 64-ushort tile global->LDS with the swizzle applied on the
// global-source side (LDS destination must stay linear for global_load_lds).
template<int ROWS, int NTHR = 256>
__device__ __forceinline__ void stage_tile(const unsigned short* gbase, size_t gstride,
                                           unsigned short* lds, int tid) {
  const int wave = tid >> 6;
#pragma unroll
  for (int rnd = 0; rnd < ROWS * 8 / NTHR; ++rnd) {
    int c = rnd * NTHR + tid;
    int row = c >> 3, pc = c & 7;
    int gcol = ((pc ^ (row & 7)) << 3);
    gload16(gbase + (size_t)row * gstride + gcol,
            lds + (size_t)(rnd * NTHR + wave * 64) * 8);
  }
}

// Plain linear stage for the PRE-PERMUTED bias tile (128 rows x 64 ushorts):
// the 8B-granular swizzle is baked into the b16 buffer by cvt_kernel, so the
// DMA is a straight copy (2 rounds at 512 threads).
__device__ __forceinline__ void stage_bias(const unsigned short* gbase,
                                           unsigned short* lds, int tid) {
  const int wave = tid >> 6;
#pragma unroll
  for (int rnd = 0; rnd < 2; ++rnd) {
    int c = rnd * 512 + tid;
    int row = c >> 3, pc = c & 7;
    gload16(gbase + (size_t)row * N_SEQ + pc * 8,
            lds + (size_t)(rnd * 512 + wave * 64) * 8);
  }
}

constexpr size_t XEL = (size_t)M_ROWS * D_MODEL;     // 4194304
constexpr size_t WEL = (size_t)D_MODEL * D_MODEL;    // 1048576
constexpr size_t BEL = (size_t)N_B * N_SEQ * N_SEQ;  // 8388608 (attn bias)
constexpr size_t TOTEL = XEL + 4 * WEL + BEL;        // 16777216

// ---------------------------------------------------------------------------
// fp32 -> bf16 convert for [x (4M) | Wq | Wk | Wv | Wo (1M each)] -> dst,
// plus bias -> f16 * log2e, PRE-PERMUTED for attn's conflict-free b64 reads:
// within each 64-key tile, 8B unit c8 of row q is stored at c8 ^ (q&15)
// (16B unit j -> j ^ ((q>>1)&7), halves swapped when q&1).
// ---------------------------------------------------------------------------
__launch_bounds__(256)
__global__ void cvt_kernel(const float* __restrict__ x, const float* __restrict__ bias,
                           const float* __restrict__ wq, const float* __restrict__ wk,
                           const float* __restrict__ wv, const float* __restrict__ wo,
                           unsigned short* __restrict__ dst,
                           unsigned short* __restrict__ dstB) {
  size_t i = ((size_t)blockIdx.x * 256 + threadIdx.x) * 8;
  if (i >= TOTEL) return;
  if (i >= XEL + 4 * WEL) {
    size_t off = i - (XEL + 4 * WEL);
    int row = (int)(off >> 11);              // global q-row (b*2048 + q)
    int key = (int)(off & 2047);
    constexpr float LOG2E = 1.44269504088896340736f;
    float4 f0 = *(const float4*)(bias + off);
    float4 f1 = *(const float4*)(bias + off + 4);
    __half t[8] = { __float2half(f0.x * LOG2E), __float2half(f0.y * LOG2E),
                    __float2half(f0.z * LOG2E), __float2half(f0.w * LOG2E),
                    __float2half(f1.x * LOG2E), __float2half(f1.y * LOG2E),
                    __float2half(f1.z * LOG2E), __float2half(f1.w * LOG2E) };
    int j  = (key >> 3) & 7;                 // 16B unit within 64-key tile
    int jp = j ^ ((row >> 1) & 7);
    uint4 v = *(const uint4*)t;
    if (row & 1) { uint4 w; w.x = v.z; w.y = v.w; w.z = v.x; w.w = v.y; v = w; }
    *(uint4*)(dstB + (((size_t)row << 11) + (key & ~63) + jp * 8)) = v;
    return;
  }
  const float* s; size_t off = i;
  if (off < XEL)                { s = x; }
  else if (off < XEL + WEL)     { s = wq; off -= XEL; }
  else if (off < XEL + 2*WEL)   { s = wk; off -= XEL + WEL; }
  else if (off < XEL + 3*WEL)   { s = wv; off -= XEL + 2*WEL; }
  else                          { s = wo; off -= XEL + 3*WEL; }
  float4 f0 = *(const float4*)(s + off);
  float4 f1 = *(const float4*)(s + off + 4);
  unsigned short t[8] = { f2bf(f0.x), f2bf(f0.y), f2bf(f0.z), f2bf(f0.w),
                          f2bf(f1.x), f2bf(f1.y), f2bf(f1.z), f2bf(f1.w) };
  *(uint4*)(dst + i) = *(const uint4*)t;
}

// ---------------------------------------------------------------------------
// m97-style 128x128 bf16 mainloop, swizzled LDS: C = A * Bw^T
// ---------------------------------------------------------------------------
__device__ __forceinline__ void mainloop128(const unsigned short* __restrict__ A,
                                            const unsigned short* __restrict__ Bw,
                                            int m0, int e0,
                                            unsigned short* As, unsigned short* Bs,
                                            f32x4 (&acc)[4][4]) {
  const int tid  = threadIdx.x;
  const int wave = tid >> 6, lane = tid & 63;
  const int l16 = lane & 15, quad = lane >> 4;
  const int wr = wave >> 1, wc = wave & 1;

  for (int kt = 0; kt < D_MODEL / 64; ++kt) {
    const int k0 = kt * 64;
    stage_tile<128>(A + (size_t)m0 * D_MODEL + k0, D_MODEL, As, tid);
    stage_tile<128>(Bw + (size_t)e0 * D_MODEL + k0, D_MODEL, Bs, tid);
    __syncthreads();
#pragma unroll
    for (int ks = 0; ks < 2; ++ks) {
      bf16x8 af[4], bfr[4];
#pragma unroll
      for (int mi = 0; mi < 4; ++mi)
        af[mi] = *(const bf16x8*)(As + lds_off(wr * 64 + mi * 16 + l16, ks * 32 + quad * 8));
#pragma unroll
      for (int ci = 0; ci < 4; ++ci)
        bfr[ci] = *(const bf16x8*)(Bs + lds_off(wc * 64 + ci * 16 + l16, ks * 32 + quad * 8));
#pragma unroll
      for (int mi = 0; mi < 4; ++mi)
#pragma unroll
        for (int ci = 0; ci < 4; ++ci)
          acc[mi][ci] = __builtin_amdgcn_mfma_f32_16x16x32_bf16(af[mi], bfr[ci], acc[mi][ci], 0, 0, 0);
    }
    __syncthreads();
  }
}

// ---------------------------------------------------------------------------
// Fused Q/K/V projection. grid (32, 24): by -> {mat = by>>3, e0 = (by&7)*128}.
// mat 0 (q): LN epilogue with 0.125*log2e softmax/exp2 scale folded in.
// mat 1 (k): LN epilogue.
// mat 2 (v): V stored TRANSPOSED per (b,h), keys sigma-permuted within each
//            32-block so attn's in-register P^T fragment lines up with V.
// ---------------------------------------------------------------------------
__launch_bounds__(256)
__global__ void qkv_gemm(const unsigned short* __restrict__ xb,
                         const unsigned short* __restrict__ wb,   // wq|wk|wv bf16
                         const float* __restrict__ bq, const float* __restrict__ bk,
                         const float* __restrict__ bv,
                         const float* __restrict__ qg, const float* __restrict__ qbeta,
                         const float* __restrict__ kg, const float* __restrict__ kbeta,
                         unsigned short* __restrict__ qkout,      // qn | kn
                         unsigned short* __restrict__ vt) {
  __shared__ unsigned short As[128 * 64];
  __shared__ unsigned short Bs[128 * 64];
  const int m0  = blockIdx.x * 128;
  const int by  = blockIdx.y;
  const int mat = by >> 3;
  const int e0  = (by & 7) * 128;
  const unsigned short* Bw = wb + (size_t)mat * WEL;

  f32x4 acc[4][4];
#pragma unroll
  for (int mi = 0; mi < 4; ++mi)
#pragma unroll
    for (int ci = 0; ci < 4; ++ci) acc[mi][ci] = f32x4{0.f, 0.f, 0.f, 0.f};

  mainloop128(xb, Bw, m0, e0, As, Bs, acc);

  const int lane = threadIdx.x & 63, wave = threadIdx.x >> 6;
  const int l16 = lane & 15, quad = lane >> 4;
  const int wr = wave >> 1, wc = wave & 1;
  const int colbase = e0 + wc * 64;          // multiple of 64 -> one head per wave

  const float* bias = (mat == 0) ? bq : ((mat == 1) ? bk : bv);
  float bcol[4];
#pragma unroll
  for (int ci = 0; ci < 4; ++ci) bcol[ci] = bias[colbase + ci * 16 + l16];
#pragma unroll
  for (int mi = 0; mi < 4; ++mi)
#pragma unroll
    for (int ci = 0; ci < 4; ++ci)
#pragma unroll
      for (int r = 0; r < 4; ++r) acc[mi][ci][r] += bcol[ci];

  if (mat < 2) {
    const float* gamma = (mat == 0) ? qg : kg;
    const float* beta  = (mat == 0) ? qbeta : kbeta;
    // fold softmax scale AND log2(e) (attn uses exp2) into q
    const float sc = (mat == 0) ? 0.18033688011112042f : 1.0f;  // 0.125*log2e
    float g4[4], bt4[4];
#pragma unroll
    for (int ci = 0; ci < 4; ++ci) {
      g4[ci] = gamma[ci * 16 + l16] * sc;
      bt4[ci] = beta[ci * 16 + l16] * sc;
    }
#pragma unroll
    for (int mi = 0; mi < 4; ++mi)
#pragma unroll
      for (int r = 0; r < 4; ++r) {
        float s = acc[mi][0][r] + acc[mi][1][r] + acc[mi][2][r] + acc[mi][3][r];
        s += __shfl_xor(s, 1); s += __shfl_xor(s, 2);
        s += __shfl_xor(s, 4); s += __shfl_xor(s, 8);
        float mean = s * (1.f / 64.f);
        float d0 = acc[mi][0][r] - mean, d1 = acc[mi][1][r] - mean;
        float d2 = acc[mi][2][r] - mean, d3 = acc[mi][3][r] - mean;
        float q = d0 * d0 + d1 * d1 + d2 * d2 + d3 * d3;
        q += __shfl_xor(q, 1); q += __shfl_xor(q, 2);
        q += __shfl_xor(q, 4); q += __shfl_xor(q, 8);
        float rs = rsqrtf(q * (1.f / 64.f) + 1e-6f);
        acc[mi][0][r] = d0 * rs * g4[0] + bt4[0];
        acc[mi][1][r] = d1 * rs * g4[1] + bt4[1];
        acc[mi][2][r] = d2 * rs * g4[2] + bt4[2];
        acc[mi][3][r] = d3 * rs * g4[3] + bt4[3];
      }
    unsigned short* out = qkout + (size_t)mat * XEL;
#pragma unroll
    for (int mi = 0; mi < 4; ++mi)
#pragma unroll
      for (int ci = 0; ci < 4; ++ci) {
        int col = colbase + ci * 16 + l16;
#pragma unroll
        for (int r = 0; r < 4; ++r) {
          int row = m0 + wr * 64 + mi * 16 + quad * 4 + r;
          out[(size_t)row * D_MODEL + col] = f2bf(acc[mi][ci][r]);
        }
      }
  } else {
    // V transpose via wave-private LDS scratch (col-swizzled), then each lane
    // stores one full d-row (128B) as 8x dwordx4 -> coalesced.
    // Token index within 64 is sigma-permuted: logical t = 16*half+4*q+r
    // stored at phys = 8*q + 4*half + r (within its 32-block), matching the
    // attention kernel's in-register P^T bf16x8 fragment order.
    unsigned short* scr = ((wave < 2) ? As : Bs) + (size_t)(wave & 1) * 4096;
#pragma unroll
    for (int ci = 0; ci < 4; ++ci) {
      int dl = ci * 16 + l16;
      int sw = (dl & 3) * 16;
#pragma unroll
      for (int mi = 0; mi < 4; ++mi)
#pragma unroll
        for (int r = 0; r < 4; ++r) {
          // logical token t = mi*16 + quad*4 + r  (half = mi&1, block = mi>>1)
          int np = ((mi >> 1) << 5) + (quad << 3) + ((mi & 1) << 2) + r;
          scr[dl * 64 + (np ^ sw)] = f2bf(acc[mi][ci][r]);
        }
    }
    __builtin_amdgcn_wave_barrier();
    int row0 = m0 + wr * 64;                 // token base of this wave's tile
    int b = row0 >> 11, nb = row0 & 2047;
    int h = colbase >> 6;
    int dl = lane;                           // this lane's d within the head
    unsigned short* gdst = vt + ((size_t)((b * 16 + h) * 64 + dl) * N_SEQ + nb);
    const unsigned short* srow = scr + dl * 64;
    int sw = (dl & 3) * 16;
#pragma unroll
    for (int j = 0; j < 8; ++j) {
      uint4 vv = *(const uint4*)(srow + ((j * 8) ^ sw));
      *(uint4*)(gdst + j * 8) = vv;
    }
  }
}

// ---------------------------------------------------------------------------
// Output projection: fp32 out = ao * Wo^T + bo. grid (32, 8).
// ---------------------------------------------------------------------------
__launch_bounds__(256)
__global__ void out_gemm(const unsigned short* __restrict__ ao,
                         const unsigned short* __restrict__ wob,
                         const float* __restrict__ bo,
                         float* __restrict__ out) {
  __shared__ unsigned short As[128 * 64];
  __shared__ unsigned short Bs[128 * 64];
  const int m0 = blockIdx.x * 128;
  const int e0 = blockIdx.y * 128;

  f32x4 acc[4][4];
#pragma unroll
  for (int mi = 0; mi < 4; ++mi)
#pragma unroll
    for (int ci = 0; ci < 4; ++ci) acc[mi][ci] = f32x4{0.f, 0.f, 0.f, 0.f};

  mainloop128(ao, wob, m0, e0, As, Bs, acc);

  const int lane = threadIdx.x & 63, wave = threadIdx.x >> 6;
  const int l16 = lane & 15, quad = lane >> 4;
  const int wr = wave >> 1, wc = wave & 1;
  float bcol[4];
#pragma unroll
  for (int ci = 0; ci < 4; ++ci) bcol[ci] = bo[e0 + wc * 64 + ci * 16 + l16];
#pragma unroll
  for (int mi = 0; mi < 4; ++mi)
#pragma unroll
    for (int ci = 0; ci < 4; ++ci) {
      int col = e0 + wc * 64 + ci * 16 + l16;
#pragma unroll
      for (int r = 0; r < 4; ++r) {
        int row = m0 + wr * 64 + mi * 16 + quad * 4 + r;
        out[(size_t)row * D_MODEL + col] = acc[mi][ci][r] + bcol[ci];
      }
    }
}

// ---------------------------------------------------------------------------
// Flash attention, swapped-operand QK^T, 8 waves / 512 threads per block.
// Wave pair (2p, 2p+1): wave 2p keys [0,32), wave 2p+1 keys [32,64) of the
// shared q-rows [p*32, p*32+32).
// R10: every DMA gets >= 1 iteration of latency cover.
//  - K depth-3 (consumed FIRST in the iter -> staged at kt-2, 2-iter cover)
//  - V depth-2 (consumed LAST -> staged at kt-1, ~1-iter cover)
//  - bias depth-2 (staged at kt-1, consumed at top of kt)
//  All stages issue at the TOP of the iteration; ONE counted wait there
//  (WAITV(4) steady; 3 at NT-2; 0 at NT-1) retires exactly [K kt+1, V kt,
//  bias kt] -- all >= 1 iter old. NO bottom-of-iter wait (R8/R9 retired the
//  same-iteration K/V stage there with only ~600cy of cover: the residual
//  stall). Barrier-only at the end of each iter.
//  - XCD swizzle (T1): 512 blocks = 8 XCDs x 64; the 16 q-tile blocks of a
//    head now share one XCD's L2 -> K/V fetched ~once per XCD.
// LDS 72KB: K 3x8K | V 2x8K | bias 2x16K; 2 blocks/CU = 144KB <= 160KB
// (R8 proved 64KBx2 resides; the old "64KB->1 block" was the VGPR cliff).
// __launch_bounds__(512,4) pins <=64 VGPR.
// ---------------------------------------------------------------------------
__launch_bounds__(512, 4)
__global__ void attn_kernel(const unsigned short* __restrict__ Q,
                            const unsigned short* __restrict__ Kn,
                            const unsigned short* __restrict__ Vt,
                            const unsigned short* __restrict__ bias16,  // f16*log2e, permuted
                            unsigned short* __restrict__ Out) {
  __shared__ unsigned short smem[36864];     // 72KB
  // K bufs:    smem + i*4096, i=0..2        [0, 12288)
  // V bufs:    smem + 12288 + i*4096        [12288, 20480)
  // bias bufs: smem + 20480 + i*8192        [20480, 36864)

  const int tid  = threadIdx.x;
  const int wave = tid >> 6, lane = tid & 63;
  const int quad = lane >> 4, l16 = lane & 15;
  const int pairId = wave >> 1;              // 4 pairs x 32 q-rows
  const int kh = wave & 1;                   // key half of the 64-key tile
  // XCD-aware bijective swizzle: hw XCD = blockIdx.x % 8; give each XCD a
  // contiguous chunk of 64 logical blocks (= 4 full heads' q-tiles).
  const int bidx0 = blockIdx.x;
  const int bidx = (bidx0 & 7) * 64 + (bidx0 >> 3);
  const int qt = bidx & 15;                  // 16 q-tiles of 128
  const int h  = (bidx >> 4) & 15;
  const int b  = bidx >> 8;
  const int q0 = qt * 128;
  const size_t base  = (size_t)b * N_SEQ * D_MODEL + (size_t)h * 64;
  const unsigned short* vtb = Vt + (size_t)(b * 16 + h) * 64 * N_SEQ;
  const unsigned short* bbase = bias16 + ((size_t)b * N_SEQ + q0) * N_SEQ;

  // ---- prologue phase 1: Q through LDS (overlays K-bufs 0/1), to regs ----
  stage_tile<128, 512>(Q + base + (size_t)q0 * D_MODEL, D_MODEL, smem, tid);
  __syncthreads();                           // Q DMA landed (vmcnt0) + barrier

  bf16x8 aq[2][2];                           // [mi][ks] — shared by the pair
#pragma unroll
  for (int mi = 0; mi < 2; ++mi)
#pragma unroll
    for (int ks = 0; ks < 2; ++ks)
      aq[mi][ks] = *(const bf16x8*)(smem + lds_off(pairId * 32 + mi * 16 + l16, ks * 32 + quad * 8));
  __syncthreads();                           // all waves read Q; safe to reuse

  // ---- prologue phase 2: stage K0, V0, bias0, K1 ----
  stage_tile<64, 512>(Kn + base, D_MODEL, smem, tid);                    // K0 (1 op)
  stage_tile<64, 512>(vtb, N_SEQ, smem + 12288, tid);                    // V0 (1 op)
  stage_bias(bbase, smem + 20480, tid);                                  // B0 (2 ops)
  stage_tile<64, 512>(Kn + base + (size_t)64 * D_MODEL, D_MODEL,
                      smem + 4096, tid);                                 // K1 (1 op)

  WAITV(1);                                  // K0,V0,B0 landed; K1 in flight
  __builtin_amdgcn_s_barrier();
  __builtin_amdgcn_sched_barrier(0);

  f32x4 o[2][4];                             // O^T partial: d = cd*16+quad*4+r, q = l16
#pragma unroll
  for (int mi = 0; mi < 2; ++mi)
#pragma unroll
    for (int cd = 0; cd < 4; ++cd) o[mi][cd] = f32x4{0.f, 0.f, 0.f, 0.f};
  float lsum[2] = {0.f, 0.f};

  constexpr int NT = N_SEQ / 64;
  for (int kt = 0; kt < NT; ++kt) {
    unsigned short* Kcur = smem + (kt % 3) * 4096;
    unsigned short* Vcur = smem + 12288 + (kt & 1) * 4096;
    const unsigned short* Bcur = smem + 20480 + (kt & 1) * 8192;

    // ---- issue this iteration's stages (top), then ONE counted wait ----
    if (kt + 2 < NT)                          // K kt+2 -> kbuf[(kt+2)%3] (1 op)
      stage_tile<64, 512>(Kn + base + (size_t)(kt + 2) * 64 * D_MODEL, D_MODEL,
                          smem + ((kt + 2) % 3) * 4096, tid);
    if (kt + 1 < NT) {                        // V kt+1 (1 op) + bias kt+1 (2 ops)
      stage_tile<64, 512>(vtb + (kt + 1) * 64, N_SEQ,
                          smem + 12288 + ((kt + 1) & 1) * 4096, tid);
      stage_bias(bbase + (kt + 1) * 64, smem + 20480 + ((kt + 1) & 1) * 8192, tid);
    }
    // retire [K kt+1, V kt, bias kt] (each issued >=1 iteration ago); keep
    // [K kt+2, V kt+1, bias kt+1] in flight
    if (kt < NT - 2)      { WAITV(4); }
    else if (kt == NT - 2){ WAITV(3); }
    else                  { WAITV(0); }

    // bias tile kt -> f32 accumulator-init values (conflict-free b64 reads;
    // c8 = kh*8 + quad + cl*4, phys = row*64 + ((c8^l16)<<2))
    f32x4 zb[2][2];
#pragma unroll
    for (int mi = 0; mi < 2; ++mi)
#pragma unroll
      for (int cl = 0; cl < 2; ++cl) {
        uint2 bw = *(const uint2*)(Bcur + (pairId * 32 + mi * 16 + l16) * 64 +
                                   (((kh * 8 + quad + cl * 4) ^ l16) << 2));
        float2 fa = __half22float2(*(const __half2*)&bw.x);
        float2 fb = __half22float2(*(const __half2*)&bw.y);
        zb[mi][cl] = f32x4{fa.x, fa.y, fb.x, fb.y};
      }

    // S^T = K Q^T + bias*log2e (bias as MFMA C-init; q pre-scaled 0.125*log2e)
    f32x4 sfT[2][2];                         // [mi][cl]: key = kh*32+cl*16+quad*4+r, q = l16
#pragma unroll
    for (int cl = 0; cl < 2; ++cl) {
      const int c = kh * 2 + cl;
      bf16x8 k0 = *(const bf16x8*)(Kcur + lds_off(c * 16 + l16, quad * 8));
      bf16x8 k1 = *(const bf16x8*)(Kcur + lds_off(c * 16 + l16, 32 + quad * 8));
      __builtin_amdgcn_s_setprio(1);
#pragma unroll
      for (int mi = 0; mi < 2; ++mi) {
        f32x4 z = __builtin_amdgcn_mfma_f32_16x16x32_bf16(k0, aq[mi][0], zb[mi][cl], 0, 0, 0);
        sfT[mi][cl] = __builtin_amdgcn_mfma_f32_16x16x32_bf16(k1, aq[mi][1], z, 0, 0, 0);
      }
      __builtin_amdgcn_s_setprio(0);
    }

    // p = 2^sfT; accumulate partial l; pack P^T (k-slot order = sigma-perm Vt)
    union PafU { unsigned int w[4]; bf16x8 v; };
    PafU paf[2];
#pragma unroll
    for (int mi = 0; mi < 2; ++mi)
#pragma unroll
      for (int cl = 0; cl < 2; ++cl) {
        float p0 = exp2fast(sfT[mi][cl][0]);
        float p1 = exp2fast(sfT[mi][cl][1]);
        float p2 = exp2fast(sfT[mi][cl][2]);
        float p3 = exp2fast(sfT[mi][cl][3]);
        lsum[mi] += (p0 + p1) + (p2 + p3);
        paf[mi].w[cl * 2]     = cvt_pk_bf16(p0, p1);
        paf[mi].w[cl * 2 + 1] = cvt_pk_bf16(p2, p3);
      }

    // O^T += V^T P^T over this wave's 32 keys (V frags reused across both mi)
    {
      bf16x8 bv[4];
#pragma unroll
      for (int cd = 0; cd < 4; ++cd)
        bv[cd] = *(const bf16x8*)(Vcur + lds_off(cd * 16 + l16, kh * 32 + quad * 8));
      __builtin_amdgcn_s_setprio(1);
#pragma unroll
      for (int mi = 0; mi < 2; ++mi)
#pragma unroll
        for (int cd = 0; cd < 4; ++cd)
          o[mi][cd] = __builtin_amdgcn_mfma_f32_16x16x32_bf16(bv[cd], paf[mi].v, o[mi][cd], 0, 0, 0);
      __builtin_amdgcn_s_setprio(0);
    }

    // barrier only (no vmcnt drain): protects next iter's buffer overwrites
    if (kt + 1 < NT) {
      __builtin_amdgcn_s_barrier();
      __builtin_amdgcn_sched_barrier(0);
    }
  }

  // drain any stragglers before reusing LDS as reduction scratch
  WAITV(0);
  __syncthreads();

  // ---- pair reduction: odd wave dumps partial O + lsum to (dead) LDS ----
  float* red = (float*)smem;                 // need 8704 floats = 34816B < 72KB
  float* slot = red + (size_t)(pairId * 64 + lane) * 34;
  if (kh) {
#pragma unroll
    for (int mi = 0; mi < 2; ++mi)
#pragma unroll
      for (int cd = 0; cd < 4; ++cd)
#pragma unroll
        for (int r = 0; r < 4; ++r)
          slot[mi * 16 + cd * 4 + r] = o[mi][cd][r];
    slot[32] = lsum[0];
    slot[33] = lsum[1];
  }
  __syncthreads();
  if (!kh) {
#pragma unroll
    for (int mi = 0; mi < 2; ++mi)
#pragma unroll
      for (int cd = 0; cd < 4; ++cd)
#pragma unroll
        for (int r = 0; r < 4; ++r)
          o[mi][cd][r] += slot[mi * 16 + cd * 4 + r];
    lsum[0] += slot[32];
    lsum[1] += slot[33];

    // normalize: lsum and O^T columns are both indexed by q = l16 -> lane-local
#pragma unroll
    for (int mi = 0; mi < 2; ++mi) {
      float l = lsum[mi];
      l += __shfl_xor(l, 16);
      l += __shfl_xor(l, 32);
      float inv = 1.0f / l;
      size_t row = (size_t)b * N_SEQ + q0 + pairId * 32 + mi * 16 + l16;
#pragma unroll
      for (int cd = 0; cd < 4; ++cd) {
        uint2 vv;
        vv.x = cvt_pk_bf16(o[mi][cd][0] * inv, o[mi][cd][1] * inv);
        vv.y = cvt_pk_bf16(o[mi][cd][2] * inv, o[mi][cd][3] * inv);
        *(uint2*)(Out + row * D_MODEL + h * 64 + cd * 16 + quad * 4) = vv;
      }
    }
  }
}

extern "C" void kernel_launch(void* const* d_in, const int* in_sizes, int n_in,
                              void* d_out, int out_size, void* d_ws, size_t ws_size,
                              hipStream_t stream) {
  const float* x    = (const float*)d_in[0];
  const float* bias = (const float*)d_in[1];
  const float* Wq = (const float*)d_in[2];  const float* bq = (const float*)d_in[3];
  const float* Wk = (const float*)d_in[4];  const float* bk = (const float*)d_in[5];
  const float* Wv = (const float*)d_in[6];  const float* bv = (const float*)d_in[7];
  const float* Wo = (const float*)d_in[8];  const float* bo = (const float*)d_in[9];
  const float* qg = (const float*)d_in[10]; const float* qb = (const float*)d_in[11];
  const float* kg = (const float*)d_in[12]; const float* kb = (const float*)d_in[13];
  float* out = (float*)d_out;

  unsigned short* wsb = (unsigned short*)d_ws;
  unsigned short* xb  = wsb;                 // 4M (reused as ao after qkv_gemm)
  unsigned short* wqb = wsb + XEL;           // 4 x 1M weights
  unsigned short* wob = wsb + XEL + 3 * WEL;
  unsigned short* qn  = wsb + XEL + 4 * WEL; // 4M
  unsigned short* kn  = qn + XEL;            // 4M
  unsigned short* vt  = qn + 2 * XEL;        // 4M, transposed + key-permuted
  unsigned short* b16 = qn + 3 * XEL;        // 8M f16 bias cache (permuted, *log2e)
  unsigned short* ao  = xb;                  // alias: xb dead after qkv_gemm

  dim3 blk(256, 1, 1);

  cvt_kernel<<<dim3((unsigned)(TOTEL / (256 * 8)), 1, 1), blk, 0, stream>>>(
      x, bias, Wq, Wk, Wv, Wo, wsb, b16);

  qkv_gemm<<<dim3(M_ROWS / 128, 24, 1), blk, 0, stream>>>(
      xb, wqb, bq, bk, bv, qg, qb, kg, kb, qn, vt);

  attn_kernel<<<dim3(N_B * 16 * (N_SEQ / 128), 1, 1), dim3(512, 1, 1), 0, stream>>>(
      qn, kn, vt, b16, ao);

  out_gemm<<<dim3(M_ROWS / 128, D_MODEL / 128, 1), blk, 0, stream>>>(ao, wob, bo, out);
}

// Round 11
// 224.145 us; speedup vs baseline: 1.1705x; 1.0391x over previous
//
#include <hip/hip_runtime.h>
#include <hip/hip_bf16.h>
#include <hip/hip_fp16.h>

#define D_MODEL 1024
#define N_SEQ   2048
#define N_B     2
#define M_ROWS  (N_B * N_SEQ)   // 4096

typedef __attribute__((ext_vector_type(8))) short bf16x8;
typedef __attribute__((ext_vector_type(4))) float f32x4;

typedef const __attribute__((address_space(1))) unsigned int gu32_t;
typedef __attribute__((address_space(3))) unsigned int lu32_t;

__device__ __forceinline__ void gload16(const void* g, void* l) {
  // async global->LDS, 16B per lane; LDS dest = wave-uniform base + lane*16
  __builtin_amdgcn_global_load_lds((gu32_t*)g, (lu32_t*)l, 16, 0, 0);
}

__device__ inline unsigned short f2bf(float f) {
  union { float f; unsigned int u; } v; v.f = f;
  unsigned int r = (v.u + 0x7FFFu + ((v.u >> 16) & 1u)) >> 16;
  return (unsigned short)r;
}

// packed f32x2 -> bf16x2 (RNE); no builtin on gfx950, per learn_hip m240
__device__ __forceinline__ unsigned int cvt_pk_bf16(float a, float b) {
  unsigned int r;
  asm("v_cvt_pk_bf16_f32 %0, %1, %2" : "=v"(r) : "v"(a), "v"(b));
  return r;
}

__device__ __forceinline__ float exp2fast(float x) {
#if __has_builtin(__builtin_amdgcn_exp2f)
  return __builtin_amdgcn_exp2f(x);
#else
  return __expf(x * 0.69314718056f);
#endif
}

// counted vmcnt wait (T4): never drain to 0 in the main loop
#define WAITV(N) asm volatile("s_waitcnt vmcnt(" #N ")" ::: "memory")

// Bank-conflict swizzle for 64-col (128B-row) LDS tiles, 16B granularity:
// logical 16B-chunk k of row r lives at physical chunk k ^ (r & 7).
__device__ __forceinline__ int lds_off(int row, int col /*ushort idx*/) {
  return row * 64 + (((col >> 3) ^ (row & 7)) << 3) + (col & 7);
}

// Stage a ROWS x 64-ushort tile global->LDS with the swizzle applied on the
// global-source side (LDS destination must stay linear for global_load_lds).
template<int ROWS, int NTHR = 256>
__device__ __forceinline__ void stage_tile(const unsigned short* gbase, size_t gstride,
                                           unsigned short* lds, int tid) {
  const int wave = tid >> 6;
#pragma unroll
  for (int rnd = 0; rnd < ROWS * 8 / NTHR; ++rnd) {
    int c = rnd * NTHR + tid;
    int row = c >> 3, pc = c & 7;
    int gcol = ((pc ^ (row & 7)) << 3);
    gload16(gbase + (size_t)row * gstride + gcol,
            lds + (size_t)(rnd * NTHR + wave * 64) * 8);
  }
}

// Plain linear stage for the PRE-PERMUTED bias tile (128 rows x 64 ushorts):
// the 8B-granular swizzle is baked into the b16 buffer by cvt_kernel, so the
// DMA is a straight copy (2 rounds at 512 threads).
__device__ __forceinline__ void stage_bias(const unsigned short* gbase,
                                           unsigned short* lds, int tid) {
  const int wave = tid >> 6;
#pragma unroll
  for (int rnd = 0; rnd < 2; ++rnd) {
    int c = rnd * 512 + tid;
    int row = c >> 3, pc = c & 7;
    gload16(gbase + (size_t)row * N_SEQ + pc * 8,
            lds + (size_t)(rnd * 512 + wave * 64) * 8);
  }
}

constexpr size_t XEL = (size_t)M_ROWS * D_MODEL;     // 4194304
constexpr size_t WEL = (size_t)D_MODEL * D_MODEL;    // 1048576
constexpr size_t BEL = (size_t)N_B * N_SEQ * N_SEQ;  // 8388608 (attn bias)
constexpr size_t TOTEL = XEL + 4 * WEL + BEL;        // 16777216

// ---------------------------------------------------------------------------
// fp32 -> bf16 convert for [x (4M) | Wq | Wk | Wv | Wo (1M each)] -> dst,
// plus bias -> f16 * log2e, PRE-PERMUTED for attn's conflict-free b64 reads:
// within each 64-key tile, 8B unit c8 of row q is stored at c8 ^ (q&15)
// (16B unit j -> j ^ ((q>>1)&7), halves swapped when q&1).
// ---------------------------------------------------------------------------
__launch_bounds__(256)
__global__ void cvt_kernel(const float* __restrict__ x, const float* __restrict__ bias,
                           const float* __restrict__ wq, const float* __restrict__ wk,
                           const float* __restrict__ wv, const float* __restrict__ wo,
                           unsigned short* __restrict__ dst,
                           unsigned short* __restrict__ dstB) {
  size_t i = ((size_t)blockIdx.x * 256 + threadIdx.x) * 8;
  if (i >= TOTEL) return;
  if (i >= XEL + 4 * WEL) {
    size_t off = i - (XEL + 4 * WEL);
    int row = (int)(off >> 11);              // global q-row (b*2048 + q)
    int key = (int)(off & 2047);
    constexpr float LOG2E = 1.44269504088896340736f;
    float4 f0 = *(const float4*)(bias + off);
    float4 f1 = *(const float4*)(bias + off + 4);
    __half t[8] = { __float2half(f0.x * LOG2E), __float2half(f0.y * LOG2E),
                    __float2half(f0.z * LOG2E), __float2half(f0.w * LOG2E),
                    __float2half(f1.x * LOG2E), __float2half(f1.y * LOG2E),
                    __float2half(f1.z * LOG2E), __float2half(f1.w * LOG2E) };
    int j  = (key >> 3) & 7;                 // 16B unit within 64-key tile
    int jp = j ^ ((row >> 1) & 7);
    uint4 v = *(const uint4*)t;
    if (row & 1) { uint4 w; w.x = v.z; w.y = v.w; w.z = v.x; w.w = v.y; v = w; }
    *(uint4*)(dstB + (((size_t)row << 11) + (key & ~63) + jp * 8)) = v;
    return;
  }
  const float* s; size_t off = i;
  if (off < XEL)                { s = x; }
  else if (off < XEL + WEL)     { s = wq; off -= XEL; }
  else if (off < XEL + 2*WEL)   { s = wk; off -= XEL + WEL; }
  else if (off < XEL + 3*WEL)   { s = wv; off -= XEL + 2*WEL; }
  else                          { s = wo; off -= XEL + 3*WEL; }
  float4 f0 = *(const float4*)(s + off);
  float4 f1 = *(const float4*)(s + off + 4);
  unsigned short t[8] = { f2bf(f0.x), f2bf(f0.y), f2bf(f0.z), f2bf(f0.w),
                          f2bf(f1.x), f2bf(f1.y), f2bf(f1.z), f2bf(f1.w) };
  *(uint4*)(dst + i) = *(const uint4*)t;
}

// ---------------------------------------------------------------------------
// R11: pipelined 128x128 bf16 mainloop (counted vmcnt, raw barriers).
// Depth-2 double-buffered A/B tiles; iteration kt issues stage kt+1 (8 DMA
// ops) at the TOP, then WAITV(8) retires stage kt (issued one full iteration
// ago -> full-iter latency cover); raw s_barrier at the bottom, NO vmcnt
// drain in the loop (the old __syncthreads drain made the kernel 360 TF /
// 13% MfmaUtil -- the m233 2-phase stall). LDS 64KB: A dbuf 2x16K, B dbuf
// 2x16K. Ends with one __syncthreads so callers may reuse smem as scratch.
// ---------------------------------------------------------------------------
__device__ __forceinline__ void mainloop128(const unsigned short* __restrict__ A,
                                            const unsigned short* __restrict__ Bw,
                                            int m0, int e0,
                                            unsigned short* smem,   // 32768 ushorts
                                            f32x4 (&acc)[4][4]) {
  const int tid  = threadIdx.x;
  const int wave = tid >> 6, lane = tid & 63;
  const int l16 = lane & 15, quad = lane >> 4;
  const int wr = wave >> 1, wc = wave & 1;
  constexpr int NT = D_MODEL / 64;   // 16

  // prologue: stage tile 0, one-time drain
  stage_tile<128>(A + (size_t)m0 * D_MODEL, D_MODEL, smem, tid);
  stage_tile<128>(Bw + (size_t)e0 * D_MODEL, D_MODEL, smem + 16384, tid);
  WAITV(0);
  __builtin_amdgcn_s_barrier();
  __builtin_amdgcn_sched_barrier(0);

  for (int kt = 0; kt < NT; ++kt) {
    const int cur = kt & 1;
    unsigned short* As = smem + cur * 8192;
    unsigned short* Bs = smem + 16384 + cur * 8192;

    if (kt + 1 < NT) {
      const int nb = cur ^ 1;                // read last at kt-1; barrier-safe
      stage_tile<128>(A + (size_t)m0 * D_MODEL + (kt + 1) * 64, D_MODEL,
                      smem + nb * 8192, tid);
      stage_tile<128>(Bw + (size_t)e0 * D_MODEL + (kt + 1) * 64, D_MODEL,
                      smem + 16384 + nb * 8192, tid);
      WAITV(8);                              // retire stage kt; kt+1 in flight
    } else {
      WAITV(0);                              // last tile fully landed
    }

#pragma unroll
    for (int ks = 0; ks < 2; ++ks) {
      bf16x8 af[4], bfr[4];
#pragma unroll
      for (int mi = 0; mi < 4; ++mi)
        af[mi] = *(const bf16x8*)(As + lds_off(wr * 64 + mi * 16 + l16, ks * 32 + quad * 8));
#pragma unroll
      for (int ci = 0; ci < 4; ++ci)
        bfr[ci] = *(const bf16x8*)(Bs + lds_off(wc * 64 + ci * 16 + l16, ks * 32 + quad * 8));
      __builtin_amdgcn_s_setprio(1);
#pragma unroll
      for (int mi = 0; mi < 4; ++mi)
#pragma unroll
        for (int ci = 0; ci < 4; ++ci)
          acc[mi][ci] = __builtin_amdgcn_mfma_f32_16x16x32_bf16(af[mi], bfr[ci], acc[mi][ci], 0, 0, 0);
      __builtin_amdgcn_s_setprio(0);
    }

    if (kt + 1 < NT) {                       // protect buf overwrite at kt+1
      __builtin_amdgcn_s_barrier();
      __builtin_amdgcn_sched_barrier(0);
    }
  }
  __syncthreads();                           // callers reuse smem as scratch
}

// ---------------------------------------------------------------------------
// Fused Q/K/V projection. grid (32, 24): by -> {mat = by>>3, e0 = (by&7)*128}.
// mat 0 (q): LN epilogue with 0.125*log2e softmax/exp2 scale folded in.
// mat 1 (k): LN epilogue.
// mat 2 (v): V stored TRANSPOSED per (b,h), keys sigma-permuted within each
//            32-block so attn's in-register P^T fragment lines up with V.
// ---------------------------------------------------------------------------
__launch_bounds__(256)
__global__ void qkv_gemm(const unsigned short* __restrict__ xb,
                         const unsigned short* __restrict__ wb,   // wq|wk|wv bf16
                         const float* __restrict__ bq, const float* __restrict__ bk,
                         const float* __restrict__ bv,
                         const float* __restrict__ qg, const float* __restrict__ qbeta,
                         const float* __restrict__ kg, const float* __restrict__ kbeta,
                         unsigned short* __restrict__ qkout,      // qn | kn
                         unsigned short* __restrict__ vt) {
  __shared__ unsigned short smem[32768];     // 64KB: A dbuf | B dbuf
  const int m0  = blockIdx.x * 128;
  const int by  = blockIdx.y;
  const int mat = by >> 3;
  const int e0  = (by & 7) * 128;
  const unsigned short* Bw = wb + (size_t)mat * WEL;

  f32x4 acc[4][4];
#pragma unroll
  for (int mi = 0; mi < 4; ++mi)
#pragma unroll
    for (int ci = 0; ci < 4; ++ci) acc[mi][ci] = f32x4{0.f, 0.f, 0.f, 0.f};

  mainloop128(xb, Bw, m0, e0, smem, acc);

  const int lane = threadIdx.x & 63, wave = threadIdx.x >> 6;
  const int l16 = lane & 15, quad = lane >> 4;
  const int wr = wave >> 1, wc = wave & 1;
  const int colbase = e0 + wc * 64;          // multiple of 64 -> one head per wave

  const float* bias = (mat == 0) ? bq : ((mat == 1) ? bk : bv);
  float bcol[4];
#pragma unroll
  for (int ci = 0; ci < 4; ++ci) bcol[ci] = bias[colbase + ci * 16 + l16];
#pragma unroll
  for (int mi = 0; mi < 4; ++mi)
#pragma unroll
    for (int ci = 0; ci < 4; ++ci)
#pragma unroll
      for (int r = 0; r < 4; ++r) acc[mi][ci][r] += bcol[ci];

  if (mat < 2) {
    const float* gamma = (mat == 0) ? qg : kg;
    const float* beta  = (mat == 0) ? qbeta : kbeta;
    // fold softmax scale AND log2(e) (attn uses exp2) into q
    const float sc = (mat == 0) ? 0.18033688011112042f : 1.0f;  // 0.125*log2e
    float g4[4], bt4[4];
#pragma unroll
    for (int ci = 0; ci < 4; ++ci) {
      g4[ci] = gamma[ci * 16 + l16] * sc;
      bt4[ci] = beta[ci * 16 + l16] * sc;
    }
#pragma unroll
    for (int mi = 0; mi < 4; ++mi)
#pragma unroll
      for (int r = 0; r < 4; ++r) {
        float s = acc[mi][0][r] + acc[mi][1][r] + acc[mi][2][r] + acc[mi][3][r];
        s += __shfl_xor(s, 1); s += __shfl_xor(s, 2);
        s += __shfl_xor(s, 4); s += __shfl_xor(s, 8);
        float mean = s * (1.f / 64.f);
        float d0 = acc[mi][0][r] - mean, d1 = acc[mi][1][r] - mean;
        float d2 = acc[mi][2][r] - mean, d3 = acc[mi][3][r] - mean;
        float q = d0 * d0 + d1 * d1 + d2 * d2 + d3 * d3;
        q += __shfl_xor(q, 1); q += __shfl_xor(q, 2);
        q += __shfl_xor(q, 4); q += __shfl_xor(q, 8);
        float rs = rsqrtf(q * (1.f / 64.f) + 1e-6f);
        acc[mi][0][r] = d0 * rs * g4[0] + bt4[0];
        acc[mi][1][r] = d1 * rs * g4[1] + bt4[1];
        acc[mi][2][r] = d2 * rs * g4[2] + bt4[2];
        acc[mi][3][r] = d3 * rs * g4[3] + bt4[3];
      }
    unsigned short* out = qkout + (size_t)mat * XEL;
#pragma unroll
    for (int mi = 0; mi < 4; ++mi)
#pragma unroll
      for (int ci = 0; ci < 4; ++ci) {
        int col = colbase + ci * 16 + l16;
#pragma unroll
        for (int r = 0; r < 4; ++r) {
          int row = m0 + wr * 64 + mi * 16 + quad * 4 + r;
          out[(size_t)row * D_MODEL + col] = f2bf(acc[mi][ci][r]);
        }
      }
  } else {
    // V transpose via wave-private LDS scratch (col-swizzled), then each lane
    // stores one full d-row (128B) as 8x dwordx4 -> coalesced.
    // Token index within 64 is sigma-permuted: logical t = 16*half+4*q+r
    // stored at phys = 8*q + 4*half + r (within its 32-block), matching the
    // attention kernel's in-register P^T bf16x8 fragment order.
    unsigned short* scr = smem + (size_t)wave * 4096;   // mainloop ended w/ barrier
#pragma unroll
    for (int ci = 0; ci < 4; ++ci) {
      int dl = ci * 16 + l16;
      int sw = (dl & 3) * 16;
#pragma unroll
      for (int mi = 0; mi < 4; ++mi)
#pragma unroll
        for (int r = 0; r < 4; ++r) {
          // logical token t = mi*16 + quad*4 + r  (half = mi&1, block = mi>>1)
          int np = ((mi >> 1) << 5) + (quad << 3) + ((mi & 1) << 2) + r;
          scr[dl * 64 + (np ^ sw)] = f2bf(acc[mi][ci][r]);
        }
    }
    __builtin_amdgcn_wave_barrier();
    int row0 = m0 + wr * 64;                 // token base of this wave's tile
    int b = row0 >> 11, nb = row0 & 2047;
    int h = colbase >> 6;
    int dl = lane;                           // this lane's d within the head
    unsigned short* gdst = vt + ((size_t)((b * 16 + h) * 64 + dl) * N_SEQ + nb);
    const unsigned short* srow = scr + dl * 64;
    int sw = (dl & 3) * 16;
#pragma unroll
    for (int j = 0; j < 8; ++j) {
      uint4 vv = *(const uint4*)(srow + ((j * 8) ^ sw));
      *(uint4*)(gdst + j * 8) = vv;
    }
  }
}

// ---------------------------------------------------------------------------
// Output projection: fp32 out = ao * Wo^T + bo. grid (32, 8).
// ---------------------------------------------------------------------------
__launch_bounds__(256)
__global__ void out_gemm(const unsigned short* __restrict__ ao,
                         const unsigned short* __restrict__ wob,
                         const float* __restrict__ bo,
                         float* __restrict__ out) {
  __shared__ unsigned short smem[32768];     // 64KB: A dbuf | B dbuf
  const int m0 = blockIdx.x * 128;
  const int e0 = blockIdx.y * 128;

  f32x4 acc[4][4];
#pragma unroll
  for (int mi = 0; mi < 4; ++mi)
#pragma unroll
    for (int ci = 0; ci < 4; ++ci) acc[mi][ci] = f32x4{0.f, 0.f, 0.f, 0.f};

  mainloop128(ao, wob, m0, e0, smem, acc);

  const int lane = threadIdx.x & 63, wave = threadIdx.x >> 6;
  const int l16 = lane & 15, quad = lane >> 4;
  const int wr = wave >> 1, wc = wave & 1;
  float bcol[4];
#pragma unroll
  for (int ci = 0; ci < 4; ++ci) bcol[ci] = bo[e0 + wc * 64 + ci * 16 + l16];
#pragma unroll
  for (int mi = 0; mi < 4; ++mi)
#pragma unroll
    for (int ci = 0; ci < 4; ++ci) {
      int col = e0 + wc * 64 + ci * 16 + l16;
#pragma unroll
      for (int r = 0; r < 4; ++r) {
        int row = m0 + wr * 64 + mi * 16 + quad * 4 + r;
        out[(size_t)row * D_MODEL + col] = acc[mi][ci][r] + bcol[ci];
      }
    }
}

// ---------------------------------------------------------------------------
// Flash attention, swapped-operand QK^T, 8 waves / 512 threads per block.
// Wave pair (2p, 2p+1): wave 2p keys [0,32), wave 2p+1 keys [32,64) of the
// shared q-rows [p*32, p*32+32).
// R10 schedule (kept): K depth-3, V depth-2, bias depth-2; all stages issue
// at the TOP of the iteration; one counted wait there (WAITV(4)/3/0) retires
// [K kt+1, V kt, bias kt] -- each >= 1 iteration old. Barrier-only at the
// bottom. XCD swizzle; bias as MFMA C-init; conflict-free bias reads.
// LDS 72KB: K 3x8K | V 2x8K | bias 2x16K. __launch_bounds__(512,4).
// ---------------------------------------------------------------------------
__launch_bounds__(512, 4)
__global__ void attn_kernel(const unsigned short* __restrict__ Q,
                            const unsigned short* __restrict__ Kn,
                            const unsigned short* __restrict__ Vt,
                            const unsigned short* __restrict__ bias16,  // f16*log2e, permuted
                            unsigned short* __restrict__ Out) {
  __shared__ unsigned short smem[36864];     // 72KB
  // K bufs:    smem + i*4096, i=0..2        [0, 12288)
  // V bufs:    smem + 12288 + i*4096        [12288, 20480)
  // bias bufs: smem + 20480 + i*8192        [20480, 36864)

  const int tid  = threadIdx.x;
  const int wave = tid >> 6, lane = tid & 63;
  const int quad = lane >> 4, l16 = lane & 15;
  const int pairId = wave >> 1;              // 4 pairs x 32 q-rows
  const int kh = wave & 1;                   // key half of the 64-key tile
  // XCD-aware bijective swizzle: hw XCD = blockIdx.x % 8; give each XCD a
  // contiguous chunk of 64 logical blocks (= 4 full heads' q-tiles).
  const int bidx0 = blockIdx.x;
  const int bidx = (bidx0 & 7) * 64 + (bidx0 >> 3);
  const int qt = bidx & 15;                  // 16 q-tiles of 128
  const int h  = (bidx >> 4) & 15;
  const int b  = bidx >> 8;
  const int q0 = qt * 128;
  const size_t base  = (size_t)b * N_SEQ * D_MODEL + (size_t)h * 64;
  const unsigned short* vtb = Vt + (size_t)(b * 16 + h) * 64 * N_SEQ;
  const unsigned short* bbase = bias16 + ((size_t)b * N_SEQ + q0) * N_SEQ;

  // ---- prologue phase 1: Q through LDS (overlays K-bufs 0/1), to regs ----
  stage_tile<128, 512>(Q + base + (size_t)q0 * D_MODEL, D_MODEL, smem, tid);
  __syncthreads();                           // Q DMA landed (vmcnt0) + barrier

  bf16x8 aq[2][2];                           // [mi][ks] — shared by the pair
#pragma unroll
  for (int mi = 0; mi < 2; ++mi)
#pragma unroll
    for (int ks = 0; ks < 2; ++ks)
      aq[mi][ks] = *(const bf16x8*)(smem + lds_off(pairId * 32 + mi * 16 + l16, ks * 32 + quad * 8));
  __syncthreads();                           // all waves read Q; safe to reuse

  // ---- prologue phase 2: stage K0, V0, bias0, K1 ----
  stage_tile<64, 512>(Kn + base, D_MODEL, smem, tid);                    // K0 (1 op)
  stage_tile<64, 512>(vtb, N_SEQ, smem + 12288, tid);                    // V0 (1 op)
  stage_bias(bbase, smem + 20480, tid);                                  // B0 (2 ops)
  stage_tile<64, 512>(Kn + base + (size_t)64 * D_MODEL, D_MODEL,
                      smem + 4096, tid);                                 // K1 (1 op)

  WAITV(1);                                  // K0,V0,B0 landed; K1 in flight
  __builtin_amdgcn_s_barrier();
  __builtin_amdgcn_sched_barrier(0);

  f32x4 o[2][4];                             // O^T partial: d = cd*16+quad*4+r, q = l16
#pragma unroll
  for (int mi = 0; mi < 2; ++mi)
#pragma unroll
    for (int cd = 0; cd < 4; ++cd) o[mi][cd] = f32x4{0.f, 0.f, 0.f, 0.f};
  float lsum[2] = {0.f, 0.f};

  constexpr int NT = N_SEQ / 64;
  for (int kt = 0; kt < NT; ++kt) {
    unsigned short* Kcur = smem + (kt % 3) * 4096;
    unsigned short* Vcur = smem + 12288 + (kt & 1) * 4096;
    const unsigned short* Bcur = smem + 20480 + (kt & 1) * 8192;

    // ---- issue this iteration's stages (top), then ONE counted wait ----
    if (kt + 2 < NT)                          // K kt+2 -> kbuf[(kt+2)%3] (1 op)
      stage_tile<64, 512>(Kn + base + (size_t)(kt + 2) * 64 * D_MODEL, D_MODEL,
                          smem + ((kt + 2) % 3) * 4096, tid);
    if (kt + 1 < NT) {                        // V kt+1 (1 op) + bias kt+1 (2 ops)
      stage_tile<64, 512>(vtb + (kt + 1) * 64, N_SEQ,
                          smem + 12288 + ((kt + 1) & 1) * 4096, tid);
      stage_bias(bbase + (kt + 1) * 64, smem + 20480 + ((kt + 1) & 1) * 8192, tid);
    }
    // retire [K kt+1, V kt, bias kt] (each issued >=1 iteration ago); keep
    // [K kt+2, V kt+1, bias kt+1] in flight
    if (kt < NT - 2)      { WAITV(4); }
    else if (kt == NT - 2){ WAITV(3); }
    else                  { WAITV(0); }

    // bias tile kt -> f32 accumulator-init values (conflict-free b64 reads;
    // c8 = kh*8 + quad + cl*4, phys = row*64 + ((c8^l16)<<2))
    f32x4 zb[2][2];
#pragma unroll
    for (int mi = 0; mi < 2; ++mi)
#pragma unroll
      for (int cl = 0; cl < 2; ++cl) {
        uint2 bw = *(const uint2*)(Bcur + (pairId * 32 + mi * 16 + l16) * 64 +
                                   (((kh * 8 + quad + cl * 4) ^ l16) << 2));
        float2 fa = __half22float2(*(const __half2*)&bw.x);
        float2 fb = __half22float2(*(const __half2*)&bw.y);
        zb[mi][cl] = f32x4{fa.x, fa.y, fb.x, fb.y};
      }

    // S^T = K Q^T + bias*log2e (bias as MFMA C-init; q pre-scaled 0.125*log2e)
    f32x4 sfT[2][2];                         // [mi][cl]: key = kh*32+cl*16+quad*4+r, q = l16
#pragma unroll
    for (int cl = 0; cl < 2; ++cl) {
      const int c = kh * 2 + cl;
      bf16x8 k0 = *(const bf16x8*)(Kcur + lds_off(c * 16 + l16, quad * 8));
      bf16x8 k1 = *(const bf16x8*)(Kcur + lds_off(c * 16 + l16, 32 + quad * 8));
      __builtin_amdgcn_s_setprio(1);
#pragma unroll
      for (int mi = 0; mi < 2; ++mi) {
        f32x4 z = __builtin_amdgcn_mfma_f32_16x16x32_bf16(k0, aq[mi][0], zb[mi][cl], 0, 0, 0);
        sfT[mi][cl] = __builtin_amdgcn_mfma_f32_16x16x32_bf16(k1, aq[mi][1], z, 0, 0, 0);
      }
      __builtin_amdgcn_s_setprio(0);
    }

    // p = 2^sfT; accumulate partial l; pack P^T (k-slot order = sigma-perm Vt)
    union PafU { unsigned int w[4]; bf16x8 v; };
    PafU paf[2];
#pragma unroll
    for (int mi = 0; mi < 2; ++mi)
#pragma unroll
      for (int cl = 0; cl < 2; ++cl) {
        float p0 = exp2fast(sfT[mi][cl][0]);
        float p1 = exp2fast(sfT[mi][cl][1]);
        float p2 = exp2fast(sfT[mi][cl][2]);
        float p3 = exp2fast(sfT[mi][cl][3]);
        lsum[mi] += (p0 + p1) + (p2 + p3);
        paf[mi].w[cl * 2]     = cvt_pk_bf16(p0, p1);
        paf[mi].w[cl * 2 + 1] = cvt_pk_bf16(p2, p3);
      }

    // O^T += V^T P^T over this wave's 32 keys (V frags reused across both mi)
    {
      bf16x8 bv[4];
#pragma unroll
      for (int cd = 0; cd < 4; ++cd)
        bv[cd] = *(const bf16x8*)(Vcur + lds_off(cd * 16 + l16, kh * 32 + quad * 8));
      __builtin_amdgcn_s_setprio(1);
#pragma unroll
      for (int mi = 0; mi < 2; ++mi)
#pragma unroll
        for (int cd = 0; cd < 4; ++cd)
          o[mi][cd] = __builtin_amdgcn_mfma_f32_16x16x32_bf16(bv[cd], paf[mi].v, o[mi][cd], 0, 0, 0);
      __builtin_amdgcn_s_setprio(0);
    }

    // barrier only (no vmcnt drain): protects next iter's buffer overwrites
    if (kt + 1 < NT) {
      __builtin_amdgcn_s_barrier();
      __builtin_amdgcn_sched_barrier(0);
    }
  }

  // drain any stragglers before reusing LDS as reduction scratch
  WAITV(0);
  __syncthreads();

  // ---- pair reduction: odd wave dumps partial O + lsum to (dead) LDS ----
  float* red = (float*)smem;                 // need 8704 floats = 34816B < 72KB
  float* slot = red + (size_t)(pairId * 64 + lane) * 34;
  if (kh) {
#pragma unroll
    for (int mi = 0; mi < 2; ++mi)
#pragma unroll
      for (int cd = 0; cd < 4; ++cd)
#pragma unroll
        for (int r = 0; r < 4; ++r)
          slot[mi * 16 + cd * 4 + r] = o[mi][cd][r];
    slot[32] = lsum[0];
    slot[33] = lsum[1];
  }
  __syncthreads();
  if (!kh) {
#pragma unroll
    for (int mi = 0; mi < 2; ++mi)
#pragma unroll
      for (int cd = 0; cd < 4; ++cd)
#pragma unroll
        for (int r = 0; r < 4; ++r)
          o[mi][cd][r] += slot[mi * 16 + cd * 4 + r];
    lsum[0] += slot[32];
    lsum[1] += slot[33];

    // normalize: lsum and O^T columns are both indexed by q = l16 -> lane-local
#pragma unroll
    for (int mi = 0; mi < 2; ++mi) {
      float l = lsum[mi];
      l += __shfl_xor(l, 16);
      l += __shfl_xor(l, 32);
      float inv = 1.0f / l;
      size_t row = (size_t)b * N_SEQ + q0 + pairId * 32 + mi * 16 + l16;
#pragma unroll
      for (int cd = 0; cd < 4; ++cd) {
        uint2 vv;
        vv.x = cvt_pk_bf16(o[mi][cd][0] * inv, o[mi][cd][1] * inv);
        vv.y = cvt_pk_bf16(o[mi][cd][2] * inv, o[mi][cd][3] * inv);
        *(uint2*)(Out + row * D_MODEL + h * 64 + cd * 16 + quad * 4) = vv;
      }
    }
  }
}

extern "C" void kernel_launch(void* const* d_in, const int* in_sizes, int n_in,
                              void* d_out, int out_size, void* d_ws, size_t ws_size,
                              hipStream_t stream) {
  const float* x    = (const float*)d_in[0];
  const float* bias = (const float*)d_in[1];
  const float* Wq = (const float*)d_in[2];  const float* bq = (const float*)d_in[3];
  const float* Wk = (const float*)d_in[4];  const float* bk = (const float*)d_in[5];
  const float* Wv = (const float*)d_in[6];  const float* bv = (const float*)d_in[7];
  const float* Wo = (const float*)d_in[8];  const float* bo = (const float*)d_in[9];
  const float* qg = (const float*)d_in[10]; const float* qb = (const float*)d_in[11];
  const float* kg = (const float*)d_in[12]; const float* kb = (const float*)d_in[13];
  float* out = (float*)d_out;

  unsigned short* wsb = (unsigned short*)d_ws;
  unsigned short* xb  = wsb;                 // 4M (reused as ao after qkv_gemm)
  unsigned short* wqb = wsb + XEL;           // 4 x 1M weights
  unsigned short* wob = wsb + XEL + 3 * WEL;
  unsigned short* qn  = wsb + XEL + 4 * WEL; // 4M
  unsigned short* kn  = qn + XEL;            // 4M
  unsigned short* vt  = qn + 2 * XEL;        // 4M, transposed + key-permuted
  unsigned short* b16 = qn + 3 * XEL;        // 8M f16 bias cache (permuted, *log2e)
  unsigned short* ao  = xb;                  // alias: xb dead after qkv_gemm

  dim3 blk(256, 1, 1);

  cvt_kernel<<<dim3((unsigned)(TOTEL / (256 * 8)), 1, 1), blk, 0, stream>>>(
      x, bias, Wq, Wk, Wv, Wo, wsb, b16);

  qkv_gemm<<<dim3(M_ROWS / 128, 24, 1), blk, 0, stream>>>(
      xb, wqb, bq, bk, bv, qg, qb, kg, kb, qn, vt);

  attn_kernel<<<dim3(N_B * 16 * (N_SEQ / 128), 1, 1), dim3(512, 1, 1), 0, stream>>>(
      qn, kn, vt, b16, ao);

  out_gemm<<<dim3(M_ROWS / 128, D_MODEL / 128, 1), blk, 0, stream>>>(ao, wob, bo, out);
}